// Round 7
// baseline (2142.110 us; speedup 1.0000x reference)
//
#include <hip/hip_runtime.h>
#include <stdint.h>

#define USER_NUM 100000
#define ITEM_NUM 200000
#define N_NODES  300000
#define EMB      64
#define NNZ      2000000
#define BATCH    4096
#define R1M      1000000u        // NNZ/2, threefry pair offset for edge dropout
#define HALF_MSG 9600000u        // N_NODES*EMB/2, pair offset for msg dropout
#define HALF_N   150000          // node pairing offset = HALF_MSG/64
#define INVK     1.1111111111111112f  // 1/0.9

#define NBUK     4688            // ceil(300000/64) row buckets
#define NSTRIPE  8
#define NSEG     (NBUK * NSTRIPE)      // 37504
#define SCAN_N   (NSEG + 1)            // 37505 (pad -> total)
#define BH_BLOCKS 320
#define BH_CHUNK (NNZ / BH_BLOCKS)     // 6250

typedef short short8 __attribute__((ext_vector_type(8)));
typedef float f32x4  __attribute__((ext_vector_type(4)));

// ---------------- threefry2x32 (exact JAX replica) ----------------
__host__ __device__ inline uint32_t rotl32(uint32_t v, int r) {
    return (v << r) | (v >> (32 - r));
}

__host__ __device__ inline void threefry2x32(uint32_t k0, uint32_t k1,
                                             uint32_t x0, uint32_t x1,
                                             uint32_t& o0, uint32_t& o1) {
    uint32_t k2 = k0 ^ k1 ^ 0x1BD11BDAu;
    x0 += k0; x1 += k1;
#define TF_R(r) { x0 += x1; x1 = rotl32(x1, r); x1 ^= x0; }
    TF_R(13) TF_R(15) TF_R(26) TF_R(6)
    x0 += k1; x1 += k2 + 1u;
    TF_R(17) TF_R(29) TF_R(16) TF_R(24)
    x0 += k2; x1 += k0 + 2u;
    TF_R(13) TF_R(15) TF_R(26) TF_R(6)
    x0 += k0; x1 += k1 + 3u;
    TF_R(17) TF_R(29) TF_R(16) TF_R(24)
    x0 += k1; x1 += k2 + 4u;
    TF_R(13) TF_R(15) TF_R(26) TF_R(6)
    x0 += k2; x1 += k0 + 5u;
#undef TF_R
    o0 = x0; o1 = x1;
}

__host__ __device__ inline float tf_uniform(uint32_t bits) {
    uint32_t fb = (bits >> 9) | 0x3f800000u;
    return __builtin_bit_cast(float, fb) - 1.0f;
}

__device__ inline bool edge_keep(uint32_t e, uint32_t kn0, uint32_t kn1) {
    uint32_t x0 = (e < R1M) ? e : e - R1M;
    uint32_t o0, o1;
    threefry2x32(kn0, kn1, x0, x0 + R1M, o0, o1);
    uint32_t bits = (e < R1M) ? o0 : o1;
    return tf_uniform(bits) < 0.9f;
}

// ---------------- bf16 helpers ----------------
__device__ inline float bf2f(uint16_t u) {
    uint32_t x = ((uint32_t)u) << 16;
    return __builtin_bit_cast(float, x);
}
__device__ inline uint16_t f2bf(float f) {   // round-to-nearest-even
    uint32_t x = __builtin_bit_cast(uint32_t, f);
    uint32_t r = (x + 0x7FFFu + ((x >> 16) & 1u)) >> 16;
    return (uint16_t)r;
}

// ---------------- ego init: concat(uemb,iemb) -> bf16 ----------------
__global__ __launch_bounds__(256) void k_conv(const float* __restrict__ u,
                                              const float* __restrict__ it,
                                              uint16_t* __restrict__ dst) {
    int i = blockIdx.x * 256 + threadIdx.x;     // quad index
    const int TOT = N_NODES * EMB / 4;          // 4.8M
    if (i >= TOT) return;
    const int UQ = USER_NUM * EMB / 4;
    float4 f = (i < UQ) ? ((const float4*)u)[i] : ((const float4*)it)[i - UQ];
    ushort4 o;
    o.x = f2bf(f.x); o.y = f2bf(f.y); o.z = f2bf(f.z); o.w = f2bf(f.w);
    ((ushort4*)dst)[i] = o;
}

// ---------------- bucket CSR build ----------------
// per-block LDS bucket histogram; flush to histBS[bucket*8 + stripe]
__global__ __launch_bounds__(256) void k_bhist(const int* __restrict__ erow,
                                               uint32_t* __restrict__ histBS,
                                               uint32_t kn0, uint32_t kn1) {
    __shared__ uint32_t cnt[NBUK];
    int tid = threadIdx.x;
    for (int i = tid; i < NBUK; i += 256) cnt[i] = 0u;
    __syncthreads();
    int base = blockIdx.x * BH_CHUNK;
    for (int j = tid; j < BH_CHUNK; j += 256) {
        int e = base + j;
        if (edge_keep((uint32_t)e, kn0, kn1))
            atomicAdd(&cnt[erow[e] >> 6], 1u);
    }
    __syncthreads();
    int stripe = blockIdx.x & 7;
    for (int i = tid; i < NBUK; i += 256) {
        uint32_t c = cnt[i];
        if (c) atomicAdd(&histBS[i * NSTRIPE + stripe], c);
    }
}

// generic 3-phase exclusive scan over n elements
__global__ __launch_bounds__(1024) void k_scan1(uint32_t* __restrict__ cnt,
                                                uint32_t* __restrict__ partials,
                                                int n) {
    __shared__ uint32_t sh[1024];
    int t = threadIdx.x;
    int i = blockIdx.x * 1024 + t;
    uint32_t x = (i < n) ? cnt[i] : 0u;
    sh[t] = x;
    __syncthreads();
    for (int off = 1; off < 1024; off <<= 1) {
        uint32_t y = (t >= off) ? sh[t - off] : 0u;
        __syncthreads();
        sh[t] += y;
        __syncthreads();
    }
    if (i < n) cnt[i] = sh[t] - x;
    if (t == 1023) partials[blockIdx.x] = sh[t];
}

__global__ __launch_bounds__(1024) void k_scan2(uint32_t* __restrict__ partials,
                                                int nblocks) {
    __shared__ uint32_t sh[1024];
    int t = threadIdx.x;
    uint32_t x = (t < nblocks) ? partials[t] : 0u;
    sh[t] = x;
    __syncthreads();
    for (int off = 1; off < 1024; off <<= 1) {
        uint32_t y = (t >= off) ? sh[t - off] : 0u;
        __syncthreads();
        sh[t] += y;
        __syncthreads();
    }
    if (t < nblocks) partials[t] = sh[t] - x;
}

// add block offsets; also copy to cursor (all but the pad element)
__global__ __launch_bounds__(1024) void k_scan3(uint32_t* __restrict__ cnt,
                                                const uint32_t* __restrict__ partials,
                                                uint32_t* __restrict__ cursor,
                                                int n) {
    int i = blockIdx.x * 1024 + threadIdx.x;
    if (i < n) {
        uint32_t v = cnt[i] + partials[blockIdx.x];
        cnt[i] = v;
        if (i < n - 1) cursor[i] = v;
    }
}

// append kept edges into bucket-stripe segments (packed col|rowlocal, val)
__global__ __launch_bounds__(256) void k_append(const int* __restrict__ erow,
                                                const int* __restrict__ ecol,
                                                const float* __restrict__ evals,
                                                uint32_t* __restrict__ cursor,
                                                uint2* __restrict__ cv,
                                                uint32_t kn0, uint32_t kn1) {
    int tid = threadIdx.x;
    int base = blockIdx.x * BH_CHUNK;
    int stripe = blockIdx.x & 7;
    for (int j = tid; j < BH_CHUNK; j += 256) {
        int e = base + j;
        if (!edge_keep((uint32_t)e, kn0, kn1)) continue;
        int row = erow[e];
        int b = row >> 6;
        uint32_t pos = atomicAdd(&cursor[b * NSTRIPE + stripe], 1u);
        uint2 p;
        p.x = (uint32_t)ecol[e] | ((uint32_t)(row & 63) << 19);
        p.y = __builtin_bit_cast(uint32_t, evals[e] * INVK);
        cv[pos] = p;
    }
}

// -------- bucketed SpMV: block per 64-row bucket, LDS f32 accumulation ------
__global__ __launch_bounds__(256) void k_spmv_bucket(
        const uint16_t* __restrict__ ego, float* __restrict__ side,
        const uint32_t* __restrict__ starts, const uint2* __restrict__ cv) {
    __shared__ float acc[64 * 65];
    int b = blockIdx.x;
    int tid = threadIdx.x;
    for (int i = tid; i < 64 * 65; i += 256) acc[i] = 0.0f;
    __syncthreads();
    uint32_t s0 = starts[b * NSTRIPE];
    uint32_t s1 = starts[(b + 1) * NSTRIPE];
    int lane = tid & 63;
    int wv = tid >> 6;
    int sub = lane >> 3;                 // edge-within-subgroup owned by this lane
    int col8 = (lane & 7) * 8;           // 8-column slice
    for (uint32_t base = s0 + (uint32_t)wv * 64u; base < s1; base += 256u) {
        int m = (int)min(64u, s1 - base);
        uint32_t meta = 0u; float v = 0.0f;
        if (lane < m) {
            uint2 p = cv[base + lane];
            meta = p.x;
            v = __builtin_bit_cast(float, p.y);
        }
        uint32_t mj[8]; float vj[8];
#pragma unroll
        for (int s = 0; s < 8; ++s) {
            mj[s] = (uint32_t)__shfl((int)meta, s * 8 + sub, 64);
            vj[s] = __shfl(v, s * 8 + sub, 64);
        }
        uint4 g[8];
#pragma unroll
        for (int s = 0; s < 8; ++s)
            g[s] = *(const uint4*)(ego + (size_t)(mj[s] & 0x7FFFFu) * 64 + col8);
#pragma unroll
        for (int s = 0; s < 8; ++s) {
            if (s * 8 >= m) break;
            float* arow = acc + (mj[s] >> 19) * 65 + col8;
            float w = vj[s];
            atomicAdd(arow + 0, w * __builtin_bit_cast(float, g[s].x << 16));
            atomicAdd(arow + 1, w * __builtin_bit_cast(float, g[s].x & 0xFFFF0000u));
            atomicAdd(arow + 2, w * __builtin_bit_cast(float, g[s].y << 16));
            atomicAdd(arow + 3, w * __builtin_bit_cast(float, g[s].y & 0xFFFF0000u));
            atomicAdd(arow + 4, w * __builtin_bit_cast(float, g[s].z << 16));
            atomicAdd(arow + 5, w * __builtin_bit_cast(float, g[s].z & 0xFFFF0000u));
            atomicAdd(arow + 6, w * __builtin_bit_cast(float, g[s].w << 16));
            atomicAdd(arow + 7, w * __builtin_bit_cast(float, g[s].w & 0xFFFF0000u));
        }
    }
    __syncthreads();
    int row0 = b * 64;
    for (int i = tid; i < 4096; i += 256) {
        int r = i >> 6, c = i & 63;
        int gr = row0 + r;
        if (gr < N_NODES) side[(size_t)gr * 64 + c] = acc[r * 65 + c];
    }
}

// -------- MFMA frag builders --------
__device__ inline short8 frag_s(f32x4 lo, f32x4 hi) {
    short8 r;
    r[0] = (short)f2bf(lo[0]); r[1] = (short)f2bf(lo[1]);
    r[2] = (short)f2bf(lo[2]); r[3] = (short)f2bf(lo[3]);
    r[4] = (short)f2bf(hi[0]); r[5] = (short)f2bf(hi[1]);
    r[6] = (short)f2bf(hi[2]); r[7] = (short)f2bf(hi[3]);
    return r;
}
__device__ inline short8 frag_t(f32x4 lo, f32x4 hi, uint4 eg) {
    short8 r;
    r[0] = (short)f2bf(lo[0] * bf2f((uint16_t)(eg.x & 0xffffu)));
    r[1] = (short)f2bf(lo[1] * bf2f((uint16_t)(eg.x >> 16)));
    r[2] = (short)f2bf(lo[2] * bf2f((uint16_t)(eg.y & 0xffffu)));
    r[3] = (short)f2bf(lo[3] * bf2f((uint16_t)(eg.y >> 16)));
    r[4] = (short)f2bf(hi[0] * bf2f((uint16_t)(eg.z & 0xffffu)));
    r[5] = (short)f2bf(hi[1] * bf2f((uint16_t)(eg.z >> 16)));
    r[6] = (short)f2bf(hi[2] * bf2f((uint16_t)(eg.w & 0xffffu)));
    r[7] = (short)f2bf(hi[3] * bf2f((uint16_t)(eg.w >> 16)));
    return r;
}

// -------- dense via MFMA: [s | ego*s] (Nx128) @ [Wg;Wb] (128x64), in-place --
__global__ __launch_bounds__(256) void k_dense_mfma(
        uint16_t* __restrict__ ego, const float* __restrict__ side,
        const float* __restrict__ Wg, const float* __restrict__ bg,
        const float* __restrict__ Wb, const float* __restrict__ bb,
        uint32_t km0, uint32_t km1) {
    int lane = threadIdx.x & 63;
    int wave = (blockIdx.x * 256 + threadIdx.x) >> 6;
    int nw = (gridDim.x * 256) >> 6;
    int m = lane & 15;     // A row within tile / C col within tile
    int g = lane >> 4;     // k-group (A) / row-group (C)

    short8 bfr[4][4];
#pragma unroll
    for (int kk = 0; kk < 4; ++kk) {
        const float* W = (kk < 2) ? Wg : Wb;
        int krow = (kk & 1) * 32 + 8 * g;
#pragma unroll
        for (int nt = 0; nt < 4; ++nt) {
#pragma unroll
            for (int i = 0; i < 8; ++i)
                bfr[kk][nt][i] = (short)f2bf(W[(krow + i) * 64 + 16 * nt + m]);
        }
    }
    float bias[4];
#pragma unroll
    for (int nt = 0; nt < 4; ++nt)
        bias[nt] = bg[16 * nt + m] + bb[16 * nt + m];

    for (int tile = wave; tile < HALF_N / 16; tile += nw) {
        int n0 = tile * 16;
        uint32_t keepB = 0;
        {
            const float*    srow = side + (size_t)(n0 + m) * 64;
            const uint16_t* erw  = ego  + (size_t)(n0 + m) * 64;
            f32x4 s0a = *(const f32x4*)(srow + 8 * g);
            f32x4 s0b = *(const f32x4*)(srow + 8 * g + 4);
            f32x4 s1a = *(const f32x4*)(srow + 32 + 8 * g);
            f32x4 s1b = *(const f32x4*)(srow + 36 + 8 * g);
            uint4 e0 = *(const uint4*)(erw + 8 * g);
            uint4 e1 = *(const uint4*)(erw + 32 + 8 * g);
            short8 a0 = frag_s(s0a, s0b);
            short8 a1 = frag_s(s1a, s1b);
            short8 a2 = frag_t(s0a, s0b, e0);
            short8 a3 = frag_t(s1a, s1b, e1);
            f32x4 acc[4];
#pragma unroll
            for (int nt = 0; nt < 4; ++nt) {
                acc[nt] = (f32x4)(0.0f);
                acc[nt] = __builtin_amdgcn_mfma_f32_16x16x32_bf16(a0, bfr[0][nt], acc[nt], 0, 0, 0);
                acc[nt] = __builtin_amdgcn_mfma_f32_16x16x32_bf16(a1, bfr[1][nt], acc[nt], 0, 0, 0);
                acc[nt] = __builtin_amdgcn_mfma_f32_16x16x32_bf16(a2, bfr[2][nt], acc[nt], 0, 0, 0);
                acc[nt] = __builtin_amdgcn_mfma_f32_16x16x32_bf16(a3, bfr[3][nt], acc[nt], 0, 0, 0);
            }
#pragma unroll
            for (int nt = 0; nt < 4; ++nt) {
#pragma unroll
                for (int i = 0; i < 4; ++i) {
                    int row = n0 + g * 4 + i;
                    int col = 16 * nt + m;
                    float h = acc[nt][i] + bias[nt];
                    h = (h >= 0.0f) ? h : 0.2f * h;
                    uint32_t j = (uint32_t)row * 64u + (uint32_t)col;
                    uint32_t o0, o1;
                    threefry2x32(km0, km1, j, j + HALF_MSG, o0, o1);
                    bool kA = tf_uniform(o0) < 0.9f;
                    keepB |= (uint32_t)(tf_uniform(o1) < 0.9f) << (nt * 4 + i);
                    ego[(size_t)row * 64 + col] = f2bf(kA ? h * INVK : 0.0f);
                }
            }
        }
        {
            int R = n0 + HALF_N;
            const float*    srow = side + (size_t)(R + m) * 64;
            const uint16_t* erw  = ego  + (size_t)(R + m) * 64;
            f32x4 s0a = *(const f32x4*)(srow + 8 * g);
            f32x4 s0b = *(const f32x4*)(srow + 8 * g + 4);
            f32x4 s1a = *(const f32x4*)(srow + 32 + 8 * g);
            f32x4 s1b = *(const f32x4*)(srow + 36 + 8 * g);
            uint4 e0 = *(const uint4*)(erw + 8 * g);
            uint4 e1 = *(const uint4*)(erw + 32 + 8 * g);
            short8 a0 = frag_s(s0a, s0b);
            short8 a1 = frag_s(s1a, s1b);
            short8 a2 = frag_t(s0a, s0b, e0);
            short8 a3 = frag_t(s1a, s1b, e1);
            f32x4 acc[4];
#pragma unroll
            for (int nt = 0; nt < 4; ++nt) {
                acc[nt] = (f32x4)(0.0f);
                acc[nt] = __builtin_amdgcn_mfma_f32_16x16x32_bf16(a0, bfr[0][nt], acc[nt], 0, 0, 0);
                acc[nt] = __builtin_amdgcn_mfma_f32_16x16x32_bf16(a1, bfr[1][nt], acc[nt], 0, 0, 0);
                acc[nt] = __builtin_amdgcn_mfma_f32_16x16x32_bf16(a2, bfr[2][nt], acc[nt], 0, 0, 0);
                acc[nt] = __builtin_amdgcn_mfma_f32_16x16x32_bf16(a3, bfr[3][nt], acc[nt], 0, 0, 0);
            }
#pragma unroll
            for (int nt = 0; nt < 4; ++nt) {
#pragma unroll
                for (int i = 0; i < 4; ++i) {
                    int row = R + g * 4 + i;
                    int col = 16 * nt + m;
                    float h = acc[nt][i] + bias[nt];
                    h = (h >= 0.0f) ? h : 0.2f * h;
                    bool kB = (keepB >> (nt * 4 + i)) & 1u;
                    ego[(size_t)row * 64 + col] = f2bf(kB ? h * INVK : 0.0f);
                }
            }
        }
    }
}

// ---------------- batch accumulation & finalize ----------------
__device__ inline float wred64(float v) {
#pragma unroll
    for (int m = 32; m >= 1; m >>= 1) v += __shfl_xor(v, m, 64);
    return v;
}

__global__ __launch_bounds__(256) void k_segacc(const void* __restrict__ ua_,
                                                const void* __restrict__ ia_,
                                                const int* __restrict__ uid,
                                                const int* __restrict__ iid,
                                                const int* __restrict__ nid,
                                                float* __restrict__ dotp,
                                                float* __restrict__ dotn,
                                                float* __restrict__ sqs,
                                                int normalize, int f32) {
    int gt = blockIdx.x * 256 + threadIdx.x;
    int w = gt >> 6, lane = gt & 63;
    if (w >= BATCH) return;
    int u = uid[w], p = iid[w], n = nid[w];
    float eu, ep, en;
    if (f32) {
        const float* ua = (const float*)ua_;
        const float* ia = (const float*)ia_;
        eu = ua[(size_t)u * EMB + lane];
        ep = ia[(size_t)p * EMB + lane];
        en = ia[(size_t)n * EMB + lane];
    } else {
        const uint16_t* ua = (const uint16_t*)ua_;
        const uint16_t* ia = (const uint16_t*)ia_;
        eu = bf2f(ua[(size_t)u * EMB + lane]);
        ep = bf2f(ia[(size_t)p * EMB + lane]);
        en = bf2f(ia[(size_t)n * EMB + lane]);
    }
    if (normalize) {
        float su = wred64(eu * eu);
        float sp = wred64(ep * ep);
        float sn = wred64(en * en);
        eu /= fmaxf(sqrtf(su), 1e-12f);
        ep /= fmaxf(sqrtf(sp), 1e-12f);
        en /= fmaxf(sqrtf(sn), 1e-12f);
    }
    float dp = wred64(eu * ep);
    float dn = wred64(eu * en);
    float s3 = wred64(eu * eu + ep * ep + en * en);
    if (lane == 0) {
        dotp[w] += dp;
        dotn[w] += dn;
        sqs[w]  += s3;
    }
}

__global__ __launch_bounds__(256) void k_finalize(const float* __restrict__ dotp,
                                                  const float* __restrict__ dotn,
                                                  const float* __restrict__ sqs,
                                                  float* __restrict__ out) {
    __shared__ float smf[256], ssq[256];
    int t = threadIdx.x;
    float mf = 0.0f, s = 0.0f;
    for (int b = t; b < BATCH; b += 256) {
        float x = dotp[b] - dotn[b];
        float ls = fminf(x, 0.0f) - log1pf(expf(-fabsf(x)));
        mf += ls;
        s += sqs[b];
    }
    smf[t] = mf; ssq[t] = s;
    __syncthreads();
    for (int off = 128; off > 0; off >>= 1) {
        if (t < off) { smf[t] += smf[t + off]; ssq[t] += ssq[t + off]; }
        __syncthreads();
    }
    if (t == 0) {
        float mf_loss = -smf[0] / (float)BATCH;
        float reg = 0.5f * ssq[0];
        float emb_loss = (float)1e-4 * reg / (float)BATCH;
        out[0] = mf_loss + emb_loss;
        out[1] = mf_loss;
        out[2] = emb_loss;
    }
}

// ---------------- launch ----------------
extern "C" void kernel_launch(void* const* d_in, const int* in_sizes, int n_in,
                              void* d_out, int out_size, void* d_ws, size_t ws_size,
                              hipStream_t stream) {
    const int*   erow  = (const int*)d_in[0];
    const int*   ecol  = (const int*)d_in[1];
    const float* evals = (const float*)d_in[2];
    const float* uemb  = (const float*)d_in[3];
    const float* iemb  = (const float*)d_in[4];
    const int*   uid   = (const int*)d_in[5];
    const int*   iid   = (const int*)d_in[6];
    const int*   nid   = (const int*)d_in[7];
    const float* Wg[3] = {(const float*)d_in[8],  (const float*)d_in[12], (const float*)d_in[16]};
    const float* bg[3] = {(const float*)d_in[9],  (const float*)d_in[13], (const float*)d_in[17]};
    const float* Wb[3] = {(const float*)d_in[10], (const float*)d_in[14], (const float*)d_in[18]};
    const float* bb[3] = {(const float*)d_in[11], (const float*)d_in[15], (const float*)d_in[19]};

    // workspace layout (~131.6 MB)
    uint2*    cv       = (uint2*)d_ws;                              // 2M uint2 (16 MB)
    float*    side     = (float*)(cv + NNZ);                        // 19.2M f32 (76.8 MB)
    uint16_t* ego      = (uint16_t*)(side + (size_t)N_NODES * EMB); // 19.2M bf16 (38.4 MB)
    uint32_t* histBS   = (uint32_t*)(ego + (size_t)N_NODES * EMB);  // 37505 u32 (-> starts)
    uint32_t* cursor   = histBS + SCAN_N;                           // 37504 u32
    uint32_t* partials = cursor + NSEG;                             // 64
    float*    dotp     = (float*)(partials + 64);                   // 4096
    float*    dotn     = dotp + BATCH;
    float*    sqs      = dotn + BATCH;
    size_t needed = (size_t)NNZ * 8 + (size_t)N_NODES * EMB * 4
                  + (size_t)N_NODES * EMB * 2
                  + ((size_t)SCAN_N + NSEG + 64 + 3 * BATCH) * 4;
    if (ws_size < needed) return;

    // host-side JAX key derivation: key(42) = (0,42)
    uint32_t a0, b0, a1, b1;
    threefry2x32(0u, 42u, 0u, 2u, a0, b0);   // split block 0
    threefry2x32(0u, 42u, 1u, 3u, a1, b1);   // split block 1
    uint32_t knode0 = a0, knode1 = a1;       // k_node
    uint32_t kmsg0  = b0, kmsg1  = b1;       // k_msg
    uint32_t mk[6];
    for (uint32_t k = 0; k < 3; ++k)
        threefry2x32(kmsg0, kmsg1, 0u, k, mk[2 * k], mk[2 * k + 1]);

    hipMemsetAsync(histBS, 0, (size_t)SCAN_N * 4, stream);
    hipMemsetAsync(dotp, 0, 3 * BATCH * 4, stream);

    // ego (bf16) init + bucket CSR build over kept edges
    k_conv<<<(N_NODES * EMB / 4 + 255) / 256, 256, 0, stream>>>(uemb, iemb, ego);
    k_bhist<<<BH_BLOCKS, 256, 0, stream>>>(erow, histBS, knode0, knode1);
    const int SB = (SCAN_N + 1023) / 1024;   // 37
    k_scan1<<<SB, 1024, 0, stream>>>(histBS, partials, SCAN_N);
    k_scan2<<<1, 1024, 0, stream>>>(partials, SB);
    k_scan3<<<SB, 1024, 0, stream>>>(histBS, partials, cursor, SCAN_N);
    k_append<<<BH_BLOCKS, 256, 0, stream>>>(erow, ecol, evals, cursor, cv,
                                            knode0, knode1);

    // segment 0: raw initial embeddings (fp32, exact)
    k_segacc<<<BATCH * 64 / 256, 256, 0, stream>>>(uemb, iemb, uid, iid, nid,
                                                   dotp, dotn, sqs, 0, 1);

    for (int k = 0; k < 3; ++k) {
        k_spmv_bucket<<<NBUK, 256, 0, stream>>>(ego, side, histBS, cv);
        k_dense_mfma<<<768, 256, 0, stream>>>(ego, side, Wg[k], bg[k], Wb[k], bb[k],
                                              mk[2 * k], mk[2 * k + 1]);
        k_segacc<<<BATCH * 64 / 256, 256, 0, stream>>>(ego, ego + (size_t)USER_NUM * EMB,
                                                       uid, iid, nid, dotp, dotn, sqs, 1, 0);
    }
    k_finalize<<<1, 256, 0, stream>>>(dotp, dotn, sqs, (float*)d_out);
}

// Round 8
// 1036.758 us; speedup vs baseline: 2.0662x; 2.0662x over previous
//
#include <hip/hip_runtime.h>
#include <stdint.h>

#define USER_NUM 100000
#define ITEM_NUM 200000
#define N_NODES  300000
#define EMB      64
#define NNZ      2000000
#define BATCH    4096
#define R1M      1000000u        // NNZ/2, threefry pair offset for edge dropout
#define HALF_MSG 9600000u        // N_NODES*EMB/2, pair offset for msg dropout
#define HALF_N   150000          // node pairing offset = HALF_MSG/64
#define INVK     1.1111111111111112f  // 1/0.9

typedef short short8 __attribute__((ext_vector_type(8)));
typedef float f32x4  __attribute__((ext_vector_type(4)));

// ---------------- threefry2x32 (exact JAX replica) ----------------
__host__ __device__ inline uint32_t rotl32(uint32_t v, int r) {
    return (v << r) | (v >> (32 - r));
}

__host__ __device__ inline void threefry2x32(uint32_t k0, uint32_t k1,
                                             uint32_t x0, uint32_t x1,
                                             uint32_t& o0, uint32_t& o1) {
    uint32_t k2 = k0 ^ k1 ^ 0x1BD11BDAu;
    x0 += k0; x1 += k1;
#define TF_R(r) { x0 += x1; x1 = rotl32(x1, r); x1 ^= x0; }
    TF_R(13) TF_R(15) TF_R(26) TF_R(6)
    x0 += k1; x1 += k2 + 1u;
    TF_R(17) TF_R(29) TF_R(16) TF_R(24)
    x0 += k2; x1 += k0 + 2u;
    TF_R(13) TF_R(15) TF_R(26) TF_R(6)
    x0 += k0; x1 += k1 + 3u;
    TF_R(17) TF_R(29) TF_R(16) TF_R(24)
    x0 += k1; x1 += k2 + 4u;
    TF_R(13) TF_R(15) TF_R(26) TF_R(6)
    x0 += k2; x1 += k0 + 5u;
#undef TF_R
    o0 = x0; o1 = x1;
}

__host__ __device__ inline float tf_uniform(uint32_t bits) {
    uint32_t fb = (bits >> 9) | 0x3f800000u;
    return __builtin_bit_cast(float, fb) - 1.0f;
}

// ---------------- bf16 helpers ----------------
__device__ inline float bf2f(uint16_t u) {
    uint32_t x = ((uint32_t)u) << 16;
    return __builtin_bit_cast(float, x);
}
__device__ inline uint16_t f2bf(float f) {   // round-to-nearest-even
    uint32_t x = __builtin_bit_cast(uint32_t, f);
    uint32_t r = (x + 0x7FFFu + ((x >> 16) & 1u)) >> 16;
    return (uint16_t)r;
}

// ---------------- edge keep mask (threefry once, bit per edge) ----------
__global__ __launch_bounds__(256) void k_mask(unsigned long long* __restrict__ mask,
                                              uint32_t kn0, uint32_t kn1) {
    int t = blockIdx.x * 256 + threadIdx.x;
    if (t >= (int)R1M) return;
    uint32_t o0, o1;
    threefry2x32(kn0, kn1, (uint32_t)t, (uint32_t)t + R1M, o0, o1);
    unsigned long long b0 = __ballot(tf_uniform(o0) < 0.9f);
    unsigned long long b1 = __ballot(tf_uniform(o1) < 0.9f);
    if ((threadIdx.x & 63) == 0) {
        mask[t >> 6] = b0;
        mask[(t + R1M) >> 6] = b1;
    }
}

__device__ inline bool keep_m(const unsigned long long* __restrict__ mask, uint32_t e) {
    return (mask[e >> 6] >> (e & 63u)) & 1ull;
}

// ---------------- ego init: concat(uemb,iemb) -> bf16 ----------------
__global__ __launch_bounds__(256) void k_conv(const float* __restrict__ u,
                                              const float* __restrict__ it,
                                              uint16_t* __restrict__ dst) {
    int i = blockIdx.x * 256 + threadIdx.x;     // quad index
    const int TOT = N_NODES * EMB / 4;          // 4.8M
    if (i >= TOT) return;
    const int UQ = USER_NUM * EMB / 4;
    float4 f = (i < UQ) ? ((const float4*)u)[i] : ((const float4*)it)[i - UQ];
    ushort4 o;
    o.x = f2bf(f.x); o.y = f2bf(f.y); o.z = f2bf(f.z); o.w = f2bf(f.w);
    ((ushort4*)dst)[i] = o;
}

// ---------------- CSR build (kept edges only) ----------------
__global__ __launch_bounds__(256) void k_hist(const int* __restrict__ erow,
                                              uint32_t* __restrict__ cnt,
                                              const unsigned long long* __restrict__ mask) {
    int e = blockIdx.x * 256 + threadIdx.x;
    if (e < NNZ && keep_m(mask, (uint32_t)e))
        atomicAdd(&cnt[erow[e]], 1u);
}

__global__ __launch_bounds__(1024) void k_scan1(uint32_t* __restrict__ cnt,
                                                uint32_t* __restrict__ partials) {
    __shared__ uint32_t sh[1024];
    int t = threadIdx.x;
    int i = blockIdx.x * 1024 + t;
    uint32_t x = (i < N_NODES) ? cnt[i] : 0u;
    sh[t] = x;
    __syncthreads();
    for (int off = 1; off < 1024; off <<= 1) {
        uint32_t y = (t >= off) ? sh[t - off] : 0u;
        __syncthreads();
        sh[t] += y;
        __syncthreads();
    }
    if (i < N_NODES) cnt[i] = sh[t] - x;
    if (t == 1023) partials[blockIdx.x] = sh[t];
}

__global__ __launch_bounds__(1024) void k_scan2(uint32_t* __restrict__ partials,
                                                int nblocks) {
    __shared__ uint32_t sh[1024];
    int t = threadIdx.x;
    uint32_t x = (t < nblocks) ? partials[t] : 0u;
    sh[t] = x;
    __syncthreads();
    for (int off = 1; off < 1024; off <<= 1) {
        uint32_t y = (t >= off) ? sh[t - off] : 0u;
        __syncthreads();
        sh[t] += y;
        __syncthreads();
    }
    if (t < nblocks) partials[t] = sh[t] - x;
}

__global__ __launch_bounds__(1024) void k_scan3(uint32_t* __restrict__ cnt,
                                                const uint32_t* __restrict__ partials) {
    int i = blockIdx.x * 1024 + threadIdx.x;
    if (i < N_NODES) cnt[i] += partials[blockIdx.x];
}

// writes packed (col, val*INVK) at sorted position
__global__ __launch_bounds__(256) void k_place(const int* __restrict__ erow,
                                               const int* __restrict__ ecol,
                                               const float* __restrict__ evals,
                                               uint32_t* __restrict__ cursor,
                                               uint2* __restrict__ cv,
                                               const unsigned long long* __restrict__ mask) {
    int e = blockIdx.x * 256 + threadIdx.x;
    if (e >= NNZ) return;
    if (!keep_m(mask, (uint32_t)e)) return;
    int r = erow[e];
    uint32_t pos = atomicAdd(&cursor[r], 1u);
    uint2 p;
    p.x = (uint32_t)ecol[e];
    p.y = __builtin_bit_cast(uint32_t, evals[e] * INVK);
    cv[pos] = p;
}

// -------- SPMV: 4 rows per wave for MLP; bf16 gather, bf16 store ----------
__global__ __launch_bounds__(256) void k_spmv(const uint16_t* __restrict__ ego,
                                              uint16_t* __restrict__ side,
                                              const uint32_t* __restrict__ cursor,
                                              const uint2* __restrict__ cv) {
    int lane = threadIdx.x & 63;
    int wave = (blockIdx.x * 256 + threadIdx.x) >> 6;
    int nw = (gridDim.x * 256) >> 6;
    for (int n0 = wave * 4; n0 < N_NODES; n0 += nw * 4) {
        uint32_t st[4], en[4];
#pragma unroll
        for (int r = 0; r < 4; ++r) {
            int n = n0 + r;
            en[r] = cursor[n];
            st[r] = (n > 0) ? cursor[n - 1] : 0u;
        }
        int c[4]; float v[4]; int m[4];
        int maxm = 0;
#pragma unroll
        for (int r = 0; r < 4; ++r) {
            m[r] = (int)min(64u, en[r] - st[r]);
            maxm = max(maxm, m[r]);
            c[r] = 0; v[r] = 0.0f;
            if (lane < m[r]) {
                uint2 p = cv[st[r] + lane];
                c[r] = (int)p.x;
                v[r] = __builtin_bit_cast(float, p.y);
            }
        }
        float acc[4] = {0.0f, 0.0f, 0.0f, 0.0f};
        for (int j0 = 0; j0 < maxm; j0 += 8) {
            float g[4][8];
#pragma unroll
            for (int r = 0; r < 4; ++r)
#pragma unroll
                for (int u = 0; u < 8; ++u)
                    if (j0 + u < m[r]) {
                        int cj = __shfl(c[r], j0 + u, 64);
                        g[r][u] = bf2f(ego[(size_t)cj * 64 + lane]);
                    }
#pragma unroll
            for (int r = 0; r < 4; ++r)
#pragma unroll
                for (int u = 0; u < 8; ++u)
                    if (j0 + u < m[r]) {
                        float vj = __shfl(v[r], j0 + u, 64);
                        acc[r] = fmaf(vj, g[r][u], acc[r]);
                    }
        }
        // degree > 64 continuation (rare)
#pragma unroll
        for (int r = 0; r < 4; ++r) {
            for (uint32_t base = st[r] + 64; base < en[r]; base += 64) {
                int mm = (int)min(64u, en[r] - base);
                int cc = 0; float vv = 0.0f;
                if (lane < mm) {
                    uint2 p = cv[base + lane];
                    cc = (int)p.x;
                    vv = __builtin_bit_cast(float, p.y);
                }
                for (int j0 = 0; j0 < mm; j0 += 8) {
                    float g[8];
#pragma unroll
                    for (int u = 0; u < 8; ++u)
                        if (j0 + u < mm) {
                            int cj = __shfl(cc, j0 + u, 64);
                            g[u] = bf2f(ego[(size_t)cj * 64 + lane]);
                        }
#pragma unroll
                    for (int u = 0; u < 8; ++u)
                        if (j0 + u < mm) {
                            float vj = __shfl(vv, j0 + u, 64);
                            acc[r] = fmaf(vj, g[u], acc[r]);
                        }
                }
            }
        }
#pragma unroll
        for (int r = 0; r < 4; ++r)
            side[(size_t)(n0 + r) * 64 + lane] = f2bf(acc[r]);
    }
}

// -------- elementwise bf16 product frag: (side ∘ ego) --------
__device__ inline short8 mul_frag(short8 s, uint4 e) {
    uint32_t ew[4] = {e.x, e.y, e.z, e.w};
    short8 r;
#pragma unroll
    for (int i = 0; i < 4; ++i) {
        float a0 = bf2f((uint16_t)s[2 * i])     * bf2f((uint16_t)(ew[i] & 0xffffu));
        float a1 = bf2f((uint16_t)s[2 * i + 1]) * bf2f((uint16_t)(ew[i] >> 16));
        r[2 * i]     = (short)f2bf(a0);
        r[2 * i + 1] = (short)f2bf(a1);
    }
    return r;
}

// -------- dense via MFMA: [s | ego*s] (Nx128) @ [Wg;Wb] (128x64), in-place --
// bf16 side -> A-frags are direct short8 loads. Pair-tile (n0, n0+150000):
// one threefry per element pair serves both tiles.
__global__ __launch_bounds__(256) void k_dense_mfma(
        uint16_t* __restrict__ ego, const uint16_t* __restrict__ side,
        const float* __restrict__ Wg, const float* __restrict__ bg,
        const float* __restrict__ Wb, const float* __restrict__ bb,
        uint32_t km0, uint32_t km1) {
    int lane = threadIdx.x & 63;
    int wave = (blockIdx.x * 256 + threadIdx.x) >> 6;
    int nw = (gridDim.x * 256) >> 6;
    int m = lane & 15;     // A row within tile / C col within tile
    int g = lane >> 4;     // k-group (A) / row-group (C)

    short8 bfr[4][4];
#pragma unroll
    for (int kk = 0; kk < 4; ++kk) {
        const float* W = (kk < 2) ? Wg : Wb;
        int krow = (kk & 1) * 32 + 8 * g;
#pragma unroll
        for (int nt = 0; nt < 4; ++nt) {
#pragma unroll
            for (int i = 0; i < 8; ++i)
                bfr[kk][nt][i] = (short)f2bf(W[(krow + i) * 64 + 16 * nt + m]);
        }
    }
    float bias[4];
#pragma unroll
    for (int nt = 0; nt < 4; ++nt)
        bias[nt] = bg[16 * nt + m] + bb[16 * nt + m];

    for (int tile = wave; tile < HALF_N / 16; tile += nw) {
        int n0 = tile * 16;
        uint32_t keepB = 0;
        {
            const uint16_t* srow = side + (size_t)(n0 + m) * 64;
            const uint16_t* erw  = ego  + (size_t)(n0 + m) * 64;
            short8 a0 = *(const short8*)(srow + 8 * g);
            short8 a1 = *(const short8*)(srow + 32 + 8 * g);
            uint4  e0 = *(const uint4*)(erw + 8 * g);
            uint4  e1 = *(const uint4*)(erw + 32 + 8 * g);
            short8 a2 = mul_frag(a0, e0);
            short8 a3 = mul_frag(a1, e1);
            f32x4 acc[4];
#pragma unroll
            for (int nt = 0; nt < 4; ++nt) {
                acc[nt] = (f32x4)(0.0f);
                acc[nt] = __builtin_amdgcn_mfma_f32_16x16x32_bf16(a0, bfr[0][nt], acc[nt], 0, 0, 0);
                acc[nt] = __builtin_amdgcn_mfma_f32_16x16x32_bf16(a1, bfr[1][nt], acc[nt], 0, 0, 0);
                acc[nt] = __builtin_amdgcn_mfma_f32_16x16x32_bf16(a2, bfr[2][nt], acc[nt], 0, 0, 0);
                acc[nt] = __builtin_amdgcn_mfma_f32_16x16x32_bf16(a3, bfr[3][nt], acc[nt], 0, 0, 0);
            }
#pragma unroll
            for (int nt = 0; nt < 4; ++nt) {
#pragma unroll
                for (int i = 0; i < 4; ++i) {
                    int row = n0 + g * 4 + i;
                    int col = 16 * nt + m;
                    float h = acc[nt][i] + bias[nt];
                    h = (h >= 0.0f) ? h : 0.2f * h;
                    uint32_t j = (uint32_t)row * 64u + (uint32_t)col;
                    uint32_t o0, o1;
                    threefry2x32(km0, km1, j, j + HALF_MSG, o0, o1);
                    bool kA = tf_uniform(o0) < 0.9f;
                    keepB |= (uint32_t)(tf_uniform(o1) < 0.9f) << (nt * 4 + i);
                    ego[(size_t)row * 64 + col] = f2bf(kA ? h * INVK : 0.0f);
                }
            }
        }
        {
            int R = n0 + HALF_N;
            const uint16_t* srow = side + (size_t)(R + m) * 64;
            const uint16_t* erw  = ego  + (size_t)(R + m) * 64;
            short8 a0 = *(const short8*)(srow + 8 * g);
            short8 a1 = *(const short8*)(srow + 32 + 8 * g);
            uint4  e0 = *(const uint4*)(erw + 8 * g);
            uint4  e1 = *(const uint4*)(erw + 32 + 8 * g);
            short8 a2 = mul_frag(a0, e0);
            short8 a3 = mul_frag(a1, e1);
            f32x4 acc[4];
#pragma unroll
            for (int nt = 0; nt < 4; ++nt) {
                acc[nt] = (f32x4)(0.0f);
                acc[nt] = __builtin_amdgcn_mfma_f32_16x16x32_bf16(a0, bfr[0][nt], acc[nt], 0, 0, 0);
                acc[nt] = __builtin_amdgcn_mfma_f32_16x16x32_bf16(a1, bfr[1][nt], acc[nt], 0, 0, 0);
                acc[nt] = __builtin_amdgcn_mfma_f32_16x16x32_bf16(a2, bfr[2][nt], acc[nt], 0, 0, 0);
                acc[nt] = __builtin_amdgcn_mfma_f32_16x16x32_bf16(a3, bfr[3][nt], acc[nt], 0, 0, 0);
            }
#pragma unroll
            for (int nt = 0; nt < 4; ++nt) {
#pragma unroll
                for (int i = 0; i < 4; ++i) {
                    int row = R + g * 4 + i;
                    int col = 16 * nt + m;
                    float h = acc[nt][i] + bias[nt];
                    h = (h >= 0.0f) ? h : 0.2f * h;
                    bool kB = (keepB >> (nt * 4 + i)) & 1u;
                    ego[(size_t)row * 64 + col] = f2bf(kB ? h * INVK : 0.0f);
                }
            }
        }
    }
}

// ---------------- batch accumulation & finalize ----------------
__device__ inline float wred64(float v) {
#pragma unroll
    for (int m = 32; m >= 1; m >>= 1) v += __shfl_xor(v, m, 64);
    return v;
}

__global__ __launch_bounds__(256) void k_segacc(const void* __restrict__ ua_,
                                                const void* __restrict__ ia_,
                                                const int* __restrict__ uid,
                                                const int* __restrict__ iid,
                                                const int* __restrict__ nid,
                                                float* __restrict__ dotp,
                                                float* __restrict__ dotn,
                                                float* __restrict__ sqs,
                                                int normalize, int f32) {
    int gt = blockIdx.x * 256 + threadIdx.x;
    int w = gt >> 6, lane = gt & 63;
    if (w >= BATCH) return;
    int u = uid[w], p = iid[w], n = nid[w];
    float eu, ep, en;
    if (f32) {
        const float* ua = (const float*)ua_;
        const float* ia = (const float*)ia_;
        eu = ua[(size_t)u * EMB + lane];
        ep = ia[(size_t)p * EMB + lane];
        en = ia[(size_t)n * EMB + lane];
    } else {
        const uint16_t* ua = (const uint16_t*)ua_;
        const uint16_t* ia = (const uint16_t*)ia_;
        eu = bf2f(ua[(size_t)u * EMB + lane]);
        ep = bf2f(ia[(size_t)p * EMB + lane]);
        en = bf2f(ia[(size_t)n * EMB + lane]);
    }
    if (normalize) {
        float su = wred64(eu * eu);
        float sp = wred64(ep * ep);
        float sn = wred64(en * en);
        eu /= fmaxf(sqrtf(su), 1e-12f);
        ep /= fmaxf(sqrtf(sp), 1e-12f);
        en /= fmaxf(sqrtf(sn), 1e-12f);
    }
    float dp = wred64(eu * ep);
    float dn = wred64(eu * en);
    float s3 = wred64(eu * eu + ep * ep + en * en);
    if (lane == 0) {
        dotp[w] += dp;
        dotn[w] += dn;
        sqs[w]  += s3;
    }
}

__global__ __launch_bounds__(256) void k_finalize(const float* __restrict__ dotp,
                                                  const float* __restrict__ dotn,
                                                  const float* __restrict__ sqs,
                                                  float* __restrict__ out) {
    __shared__ float smf[256], ssq[256];
    int t = threadIdx.x;
    float mf = 0.0f, s = 0.0f;
    for (int b = t; b < BATCH; b += 256) {
        float x = dotp[b] - dotn[b];
        float ls = fminf(x, 0.0f) - log1pf(expf(-fabsf(x)));
        mf += ls;
        s += sqs[b];
    }
    smf[t] = mf; ssq[t] = s;
    __syncthreads();
    for (int off = 128; off > 0; off >>= 1) {
        if (t < off) { smf[t] += smf[t + off]; ssq[t] += ssq[t + off]; }
        __syncthreads();
    }
    if (t == 0) {
        float mf_loss = -smf[0] / (float)BATCH;
        float reg = 0.5f * ssq[0];
        float emb_loss = (float)1e-4 * reg / (float)BATCH;
        out[0] = mf_loss + emb_loss;
        out[1] = mf_loss;
        out[2] = emb_loss;
    }
}

// ---------------- launch ----------------
extern "C" void kernel_launch(void* const* d_in, const int* in_sizes, int n_in,
                              void* d_out, int out_size, void* d_ws, size_t ws_size,
                              hipStream_t stream) {
    const int*   erow  = (const int*)d_in[0];
    const int*   ecol  = (const int*)d_in[1];
    const float* evals = (const float*)d_in[2];
    const float* uemb  = (const float*)d_in[3];
    const float* iemb  = (const float*)d_in[4];
    const int*   uid   = (const int*)d_in[5];
    const int*   iid   = (const int*)d_in[6];
    const int*   nid   = (const int*)d_in[7];
    const float* Wg[3] = {(const float*)d_in[8],  (const float*)d_in[12], (const float*)d_in[16]};
    const float* bg[3] = {(const float*)d_in[9],  (const float*)d_in[13], (const float*)d_in[17]};
    const float* Wb[3] = {(const float*)d_in[10], (const float*)d_in[14], (const float*)d_in[18]};
    const float* bb[3] = {(const float*)d_in[11], (const float*)d_in[15], (const float*)d_in[19]};

    // workspace layout (~94 MB)
    uint2*    cv       = (uint2*)d_ws;                              // 2M uint2 (16 MB)
    unsigned long long* mask = (unsigned long long*)(cv + NNZ);     // 31250 u64 (250 KB)
    uint16_t* side     = (uint16_t*)(mask + NNZ / 64);              // 19.2M bf16 (38.4 MB)
    uint16_t* ego      = side + (size_t)N_NODES * EMB;              // 19.2M bf16 (38.4 MB)
    uint32_t* cursor   = (uint32_t*)(ego + (size_t)N_NODES * EMB);  // 300000 u32
    uint32_t* partials = cursor + N_NODES;                          // 1024
    float*    dotp     = (float*)(partials + 1024);                 // 4096
    float*    dotn     = dotp + BATCH;
    float*    sqs      = dotn + BATCH;
    size_t needed = (size_t)NNZ * 8 + (size_t)(NNZ / 64) * 8
                  + (size_t)N_NODES * EMB * 2 * 2
                  + ((size_t)N_NODES + 1024 + 3 * BATCH) * 4;
    if (ws_size < needed) return;

    // host-side JAX key derivation: key(42) = (0,42)
    uint32_t a0, b0, a1, b1;
    threefry2x32(0u, 42u, 0u, 2u, a0, b0);   // split block 0
    threefry2x32(0u, 42u, 1u, 3u, a1, b1);   // split block 1
    uint32_t knode0 = a0, knode1 = a1;       // k_node
    uint32_t kmsg0  = b0, kmsg1  = b1;       // k_msg
    uint32_t mk[6];
    for (uint32_t k = 0; k < 3; ++k)
        threefry2x32(kmsg0, kmsg1, 0u, k, mk[2 * k], mk[2 * k + 1]);

    hipMemsetAsync(cursor, 0, (size_t)N_NODES * 4, stream);
    hipMemsetAsync(dotp, 0, 3 * BATCH * 4, stream);

    // ego (bf16) init + keep-mask + CSR build over kept edges
    k_conv<<<(N_NODES * EMB / 4 + 255) / 256, 256, 0, stream>>>(uemb, iemb, ego);
    k_mask<<<((int)R1M + 255) / 256, 256, 0, stream>>>(mask, knode0, knode1);
    const int SCAN_BLOCKS = (N_NODES + 1023) / 1024;  // 293
    k_hist<<<(NNZ + 255) / 256, 256, 0, stream>>>(erow, cursor, mask);
    k_scan1<<<SCAN_BLOCKS, 1024, 0, stream>>>(cursor, partials);
    k_scan2<<<1, 1024, 0, stream>>>(partials, SCAN_BLOCKS);
    k_scan3<<<SCAN_BLOCKS, 1024, 0, stream>>>(cursor, partials);
    k_place<<<(NNZ + 255) / 256, 256, 0, stream>>>(erow, ecol, evals, cursor, cv, mask);

    // segment 0: raw initial embeddings (fp32, exact)
    k_segacc<<<BATCH * 64 / 256, 256, 0, stream>>>(uemb, iemb, uid, iid, nid,
                                                   dotp, dotn, sqs, 0, 1);

    for (int k = 0; k < 3; ++k) {
        k_spmv<<<2048, 256, 0, stream>>>(ego, side, cursor, cv);
        k_dense_mfma<<<768, 256, 0, stream>>>(ego, side, Wg[k], bg[k], Wb[k], bb[k],
                                              mk[2 * k], mk[2 * k + 1]);
        k_segacc<<<BATCH * 64 / 256, 256, 0, stream>>>(ego, ego + (size_t)USER_NUM * EMB,
                                                       uid, iid, nid, dotp, dotn, sqs, 1, 0);
    }
    k_finalize<<<1, 256, 0, stream>>>(dotp, dotn, sqs, (float*)d_out);
}

// Round 9
// 642.585 us; speedup vs baseline: 3.3336x; 1.6134x over previous
//
#include <hip/hip_runtime.h>
#include <stdint.h>

#define USER_NUM 100000
#define ITEM_NUM 200000
#define N_NODES  300000
#define EMB      64
#define NNZ      2000000
#define BATCH    4096
#define R1M      1000000u        // NNZ/2, threefry pair offset for edge dropout
#define HALF_MSG 9600000u        // N_NODES*EMB/2, pair offset for msg dropout
#define HALF_N   150000          // node pairing offset = HALF_MSG/64
#define INVK     1.1111111111111112f  // 1/0.9

#define NBK      2344            // ceil(300000/128) buckets of 128 rows
#define BCAP     1152            // bucket capacity (expected max ~968 raw)

typedef short short8 __attribute__((ext_vector_type(8)));
typedef float f32x4  __attribute__((ext_vector_type(4)));

// ---------------- threefry2x32 (exact JAX replica) ----------------
__host__ __device__ inline uint32_t rotl32(uint32_t v, int r) {
    return (v << r) | (v >> (32 - r));
}

__host__ __device__ inline void threefry2x32(uint32_t k0, uint32_t k1,
                                             uint32_t x0, uint32_t x1,
                                             uint32_t& o0, uint32_t& o1) {
    uint32_t k2 = k0 ^ k1 ^ 0x1BD11BDAu;
    x0 += k0; x1 += k1;
#define TF_R(r) { x0 += x1; x1 = rotl32(x1, r); x1 ^= x0; }
    TF_R(13) TF_R(15) TF_R(26) TF_R(6)
    x0 += k1; x1 += k2 + 1u;
    TF_R(17) TF_R(29) TF_R(16) TF_R(24)
    x0 += k2; x1 += k0 + 2u;
    TF_R(13) TF_R(15) TF_R(26) TF_R(6)
    x0 += k0; x1 += k1 + 3u;
    TF_R(17) TF_R(29) TF_R(16) TF_R(24)
    x0 += k1; x1 += k2 + 4u;
    TF_R(13) TF_R(15) TF_R(26) TF_R(6)
    x0 += k2; x1 += k0 + 5u;
#undef TF_R
    o0 = x0; o1 = x1;
}

__host__ __device__ inline float tf_uniform(uint32_t bits) {
    uint32_t fb = (bits >> 9) | 0x3f800000u;
    return __builtin_bit_cast(float, fb) - 1.0f;
}

// ---------------- bf16 helpers ----------------
__device__ inline float bf2f(uint16_t u) {
    uint32_t x = ((uint32_t)u) << 16;
    return __builtin_bit_cast(float, x);
}
__device__ inline uint16_t f2bf(float f) {   // round-to-nearest-even
    uint32_t x = __builtin_bit_cast(uint32_t, f);
    uint32_t r = (x + 0x7FFFu + ((x >> 16) & 1u)) >> 16;
    return (uint16_t)r;
}

// ---------------- edge keep mask (threefry once, bit per edge) ----------
__global__ __launch_bounds__(256) void k_mask(unsigned long long* __restrict__ mask,
                                              uint32_t kn0, uint32_t kn1) {
    int t = blockIdx.x * 256 + threadIdx.x;
    if (t >= (int)R1M) return;
    uint32_t o0, o1;
    threefry2x32(kn0, kn1, (uint32_t)t, (uint32_t)t + R1M, o0, o1);
    unsigned long long b0 = __ballot(tf_uniform(o0) < 0.9f);
    unsigned long long b1 = __ballot(tf_uniform(o1) < 0.9f);
    if ((threadIdx.x & 63) == 0) {
        mask[t >> 6] = b0;
        mask[(t + R1M) >> 6] = b1;
    }
}

__device__ inline bool keep_m(const unsigned long long* __restrict__ mask, uint32_t e) {
    return (mask[e >> 6] >> (e & 63u)) & 1ull;
}

// ---------------- ego init: concat(uemb,iemb) -> bf16 ----------------
__global__ __launch_bounds__(256) void k_conv(const float* __restrict__ u,
                                              const float* __restrict__ it,
                                              uint16_t* __restrict__ dst) {
    int i = blockIdx.x * 256 + threadIdx.x;     // quad index
    const int TOT = N_NODES * EMB / 4;          // 4.8M
    if (i >= TOT) return;
    const int UQ = USER_NUM * EMB / 4;
    float4 f = (i < UQ) ? ((const float4*)u)[i] : ((const float4*)it)[i - UQ];
    ushort4 o;
    o.x = f2bf(f.x); o.y = f2bf(f.y); o.z = f2bf(f.z); o.w = f2bf(f.w);
    ((ushort4*)dst)[i] = o;
}

// ---------------- bucket sort pass A: scatter into 128-row buckets --------
__global__ __launch_bounds__(256) void k_bscatter(const int* __restrict__ erow,
                                                  const int* __restrict__ ecol,
                                                  const float* __restrict__ evals,
                                                  const unsigned long long* __restrict__ mask,
                                                  uint32_t* __restrict__ bcnt,
                                                  uint2* __restrict__ tmp) {
    int e = blockIdx.x * 256 + threadIdx.x;
    if (e >= NNZ) return;
    if (!keep_m(mask, (uint32_t)e)) return;
    int row = erow[e];
    int b = row >> 7;
    uint32_t pos = atomicAdd(&bcnt[b], 1u);
    if (pos >= BCAP) return;   // statistical impossibility; protects memory
    uint2 p;
    p.x = (uint32_t)ecol[e] | ((uint32_t)(row & 127) << 19);
    p.y = __builtin_bit_cast(uint32_t, evals[e] * INVK);
    tmp[(size_t)b * BCAP + pos] = p;
}

// ---------------- bucket sort pass B: within-bucket row sort --------------
// One block per bucket. Emits rowstart/rowend and row-sorted cv.
__global__ __launch_bounds__(128) void k_bsort(const uint2* __restrict__ tmp,
                                               const uint32_t* __restrict__ bcnt,
                                               uint2* __restrict__ cv,
                                               uint32_t* __restrict__ rowstart,
                                               uint32_t* __restrict__ rowend) {
    __shared__ uint32_t hist[128];
    __shared__ uint32_t scn[128];
    __shared__ uint32_t cur[128];
    int b = blockIdx.x;
    int t = threadIdx.x;
    uint32_t cnt = min(bcnt[b], (uint32_t)BCAP);
    hist[t] = 0u;
    __syncthreads();
    const uint2* src = tmp + (size_t)b * BCAP;
    for (uint32_t i = t; i < cnt; i += 128)
        atomicAdd(&hist[src[i].x >> 19], 1u);
    __syncthreads();
    uint32_t x = hist[t];
    scn[t] = x;
    __syncthreads();
    for (int off = 1; off < 128; off <<= 1) {
        uint32_t y = (t >= off) ? scn[t - off] : 0u;
        __syncthreads();
        scn[t] += y;
        __syncthreads();
    }
    uint32_t inc = scn[t];
    uint32_t exc = inc - x;
    uint32_t base = (uint32_t)b * BCAP;
    int row = b * 128 + t;
    if (row < N_NODES) {
        rowstart[row] = base + exc;
        rowend[row]   = base + inc;
    }
    cur[t] = exc;
    __syncthreads();
    for (uint32_t i = t; i < cnt; i += 128) {
        uint2 p = src[i];
        uint32_t rl = p.x >> 19;
        uint32_t pos = atomicAdd(&cur[rl], 1u);
        uint2 q;
        q.x = p.x & 0x7FFFFu;
        q.y = p.y;
        cv[(size_t)base + pos] = q;
    }
}

// -------- SPMV: wave per row; scalar (SGPR) metadata, 8-deep gathers ------
__global__ __launch_bounds__(256) void k_spmv(const uint16_t* __restrict__ ego,
                                              uint16_t* __restrict__ side,
                                              const uint32_t* __restrict__ rowstart,
                                              const uint32_t* __restrict__ rowend,
                                              const uint2* __restrict__ cv) {
    int lane = threadIdx.x & 63;
    int wv = __builtin_amdgcn_readfirstlane((int)((blockIdx.x * 256 + threadIdx.x) >> 6));
    int nw = (gridDim.x * 256) >> 6;
    for (int n = wv; n < N_NODES; n += nw) {
        uint32_t st = __builtin_amdgcn_readfirstlane(rowstart[n]);
        uint32_t en = __builtin_amdgcn_readfirstlane(rowend[n]);
        float acc = 0.0f;
        for (uint32_t j0 = st; j0 < en; j0 += 8) {
            uint32_t cx[8];
            float vv[8];
#pragma unroll
            for (int u = 0; u < 8; ++u) {
                uint2 p = cv[j0 + u];            // uniform addr -> scalar load
                bool ok = (j0 + (uint32_t)u) < en;
                cx[u] = ok ? p.x : 0u;           // uniform selects (SALU)
                vv[u] = ok ? __builtin_bit_cast(float, p.y) : 0.0f;
            }
            float g[8];
#pragma unroll
            for (int u = 0; u < 8; ++u)
                g[u] = bf2f(ego[(size_t)cx[u] * 64 + lane]);
#pragma unroll
            for (int u = 0; u < 8; ++u)
                acc = fmaf(vv[u], g[u], acc);
        }
        side[(size_t)n * 64 + lane] = f2bf(acc);
    }
}

// -------- elementwise bf16 product frag: (side ∘ ego) --------
__device__ inline short8 mul_frag(short8 s, uint4 e) {
    uint32_t ew[4] = {e.x, e.y, e.z, e.w};
    short8 r;
#pragma unroll
    for (int i = 0; i < 4; ++i) {
        float a0 = bf2f((uint16_t)s[2 * i])     * bf2f((uint16_t)(ew[i] & 0xffffu));
        float a1 = bf2f((uint16_t)s[2 * i + 1]) * bf2f((uint16_t)(ew[i] >> 16));
        r[2 * i]     = (short)f2bf(a0);
        r[2 * i + 1] = (short)f2bf(a1);
    }
    return r;
}

// -------- dense via MFMA: [s | ego*s] (Nx128) @ [Wg;Wb] (128x64), in-place --
// Pair-tile (n0, n0+150000): one threefry per element pair serves both tiles.
__global__ __launch_bounds__(256) void k_dense_mfma(
        uint16_t* __restrict__ ego, const uint16_t* __restrict__ side,
        const float* __restrict__ Wg, const float* __restrict__ bg,
        const float* __restrict__ Wb, const float* __restrict__ bb,
        uint32_t km0, uint32_t km1) {
    int lane = threadIdx.x & 63;
    int wave = (blockIdx.x * 256 + threadIdx.x) >> 6;
    int nw = (gridDim.x * 256) >> 6;
    int m = lane & 15;     // A row within tile / C col within tile
    int g = lane >> 4;     // k-group (A) / row-group (C)

    short8 bfr[4][4];
#pragma unroll
    for (int kk = 0; kk < 4; ++kk) {
        const float* W = (kk < 2) ? Wg : Wb;
        int krow = (kk & 1) * 32 + 8 * g;
#pragma unroll
        for (int nt = 0; nt < 4; ++nt) {
#pragma unroll
            for (int i = 0; i < 8; ++i)
                bfr[kk][nt][i] = (short)f2bf(W[(krow + i) * 64 + 16 * nt + m]);
        }
    }
    float bias[4];
#pragma unroll
    for (int nt = 0; nt < 4; ++nt)
        bias[nt] = bg[16 * nt + m] + bb[16 * nt + m];

    for (int tile = wave; tile < HALF_N / 16; tile += nw) {
        int n0 = tile * 16;
        uint32_t keepB = 0;
        {
            const uint16_t* srow = side + (size_t)(n0 + m) * 64;
            const uint16_t* erw  = ego  + (size_t)(n0 + m) * 64;
            short8 a0 = *(const short8*)(srow + 8 * g);
            short8 a1 = *(const short8*)(srow + 32 + 8 * g);
            uint4  e0 = *(const uint4*)(erw + 8 * g);
            uint4  e1 = *(const uint4*)(erw + 32 + 8 * g);
            short8 a2 = mul_frag(a0, e0);
            short8 a3 = mul_frag(a1, e1);
            f32x4 acc[4];
#pragma unroll
            for (int nt = 0; nt < 4; ++nt) {
                acc[nt] = (f32x4)(0.0f);
                acc[nt] = __builtin_amdgcn_mfma_f32_16x16x32_bf16(a0, bfr[0][nt], acc[nt], 0, 0, 0);
                acc[nt] = __builtin_amdgcn_mfma_f32_16x16x32_bf16(a1, bfr[1][nt], acc[nt], 0, 0, 0);
                acc[nt] = __builtin_amdgcn_mfma_f32_16x16x32_bf16(a2, bfr[2][nt], acc[nt], 0, 0, 0);
                acc[nt] = __builtin_amdgcn_mfma_f32_16x16x32_bf16(a3, bfr[3][nt], acc[nt], 0, 0, 0);
            }
#pragma unroll
            for (int nt = 0; nt < 4; ++nt) {
#pragma unroll
                for (int i = 0; i < 4; ++i) {
                    int row = n0 + g * 4 + i;
                    int col = 16 * nt + m;
                    float h = acc[nt][i] + bias[nt];
                    h = (h >= 0.0f) ? h : 0.2f * h;
                    uint32_t j = (uint32_t)row * 64u + (uint32_t)col;
                    uint32_t o0, o1;
                    threefry2x32(km0, km1, j, j + HALF_MSG, o0, o1);
                    bool kA = tf_uniform(o0) < 0.9f;
                    keepB |= (uint32_t)(tf_uniform(o1) < 0.9f) << (nt * 4 + i);
                    ego[(size_t)row * 64 + col] = f2bf(kA ? h * INVK : 0.0f);
                }
            }
        }
        {
            int R = n0 + HALF_N;
            const uint16_t* srow = side + (size_t)(R + m) * 64;
            const uint16_t* erw  = ego  + (size_t)(R + m) * 64;
            short8 a0 = *(const short8*)(srow + 8 * g);
            short8 a1 = *(const short8*)(srow + 32 + 8 * g);
            uint4  e0 = *(const uint4*)(erw + 8 * g);
            uint4  e1 = *(const uint4*)(erw + 32 + 8 * g);
            short8 a2 = mul_frag(a0, e0);
            short8 a3 = mul_frag(a1, e1);
            f32x4 acc[4];
#pragma unroll
            for (int nt = 0; nt < 4; ++nt) {
                acc[nt] = (f32x4)(0.0f);
                acc[nt] = __builtin_amdgcn_mfma_f32_16x16x32_bf16(a0, bfr[0][nt], acc[nt], 0, 0, 0);
                acc[nt] = __builtin_amdgcn_mfma_f32_16x16x32_bf16(a1, bfr[1][nt], acc[nt], 0, 0, 0);
                acc[nt] = __builtin_amdgcn_mfma_f32_16x16x32_bf16(a2, bfr[2][nt], acc[nt], 0, 0, 0);
                acc[nt] = __builtin_amdgcn_mfma_f32_16x16x32_bf16(a3, bfr[3][nt], acc[nt], 0, 0, 0);
            }
#pragma unroll
            for (int nt = 0; nt < 4; ++nt) {
#pragma unroll
                for (int i = 0; i < 4; ++i) {
                    int row = R + g * 4 + i;
                    int col = 16 * nt + m;
                    float h = acc[nt][i] + bias[nt];
                    h = (h >= 0.0f) ? h : 0.2f * h;
                    bool kB = (keepB >> (nt * 4 + i)) & 1u;
                    ego[(size_t)row * 64 + col] = f2bf(kB ? h * INVK : 0.0f);
                }
            }
        }
    }
}

// ---------------- batch accumulation & finalize ----------------
__device__ inline float wred64(float v) {
#pragma unroll
    for (int m = 32; m >= 1; m >>= 1) v += __shfl_xor(v, m, 64);
    return v;
}

__global__ __launch_bounds__(256) void k_segacc(const void* __restrict__ ua_,
                                                const void* __restrict__ ia_,
                                                const int* __restrict__ uid,
                                                const int* __restrict__ iid,
                                                const int* __restrict__ nid,
                                                float* __restrict__ dotp,
                                                float* __restrict__ dotn,
                                                float* __restrict__ sqs,
                                                int normalize, int f32) {
    int gt = blockIdx.x * 256 + threadIdx.x;
    int w = gt >> 6, lane = gt & 63;
    if (w >= BATCH) return;
    int u = uid[w], p = iid[w], n = nid[w];
    float eu, ep, en;
    if (f32) {
        const float* ua = (const float*)ua_;
        const float* ia = (const float*)ia_;
        eu = ua[(size_t)u * EMB + lane];
        ep = ia[(size_t)p * EMB + lane];
        en = ia[(size_t)n * EMB + lane];
    } else {
        const uint16_t* ua = (const uint16_t*)ua_;
        const uint16_t* ia = (const uint16_t*)ia_;
        eu = bf2f(ua[(size_t)u * EMB + lane]);
        ep = bf2f(ia[(size_t)p * EMB + lane]);
        en = bf2f(ia[(size_t)n * EMB + lane]);
    }
    if (normalize) {
        float su = wred64(eu * eu);
        float sp = wred64(ep * ep);
        float sn = wred64(en * en);
        eu /= fmaxf(sqrtf(su), 1e-12f);
        ep /= fmaxf(sqrtf(sp), 1e-12f);
        en /= fmaxf(sqrtf(sn), 1e-12f);
    }
    float dp = wred64(eu * ep);
    float dn = wred64(eu * en);
    float s3 = wred64(eu * eu + ep * ep + en * en);
    if (lane == 0) {
        dotp[w] += dp;
        dotn[w] += dn;
        sqs[w]  += s3;
    }
}

__global__ __launch_bounds__(256) void k_finalize(const float* __restrict__ dotp,
                                                  const float* __restrict__ dotn,
                                                  const float* __restrict__ sqs,
                                                  float* __restrict__ out) {
    __shared__ float smf[256], ssq[256];
    int t = threadIdx.x;
    float mf = 0.0f, s = 0.0f;
    for (int b = t; b < BATCH; b += 256) {
        float x = dotp[b] - dotn[b];
        float ls = fminf(x, 0.0f) - log1pf(expf(-fabsf(x)));
        mf += ls;
        s += sqs[b];
    }
    smf[t] = mf; ssq[t] = s;
    __syncthreads();
    for (int off = 128; off > 0; off >>= 1) {
        if (t < off) { smf[t] += smf[t + off]; ssq[t] += ssq[t + off]; }
        __syncthreads();
    }
    if (t == 0) {
        float mf_loss = -smf[0] / (float)BATCH;
        float reg = 0.5f * ssq[0];
        float emb_loss = (float)1e-4 * reg / (float)BATCH;
        out[0] = mf_loss + emb_loss;
        out[1] = mf_loss;
        out[2] = emb_loss;
    }
}

// ---------------- launch ----------------
extern "C" void kernel_launch(void* const* d_in, const int* in_sizes, int n_in,
                              void* d_out, int out_size, void* d_ws, size_t ws_size,
                              hipStream_t stream) {
    const int*   erow  = (const int*)d_in[0];
    const int*   ecol  = (const int*)d_in[1];
    const float* evals = (const float*)d_in[2];
    const float* uemb  = (const float*)d_in[3];
    const float* iemb  = (const float*)d_in[4];
    const int*   uid   = (const int*)d_in[5];
    const int*   iid   = (const int*)d_in[6];
    const int*   nid   = (const int*)d_in[7];
    const float* Wg[3] = {(const float*)d_in[8],  (const float*)d_in[12], (const float*)d_in[16]};
    const float* bg[3] = {(const float*)d_in[9],  (const float*)d_in[13], (const float*)d_in[17]};
    const float* Wb[3] = {(const float*)d_in[10], (const float*)d_in[14], (const float*)d_in[18]};
    const float* bb[3] = {(const float*)d_in[11], (const float*)d_in[15], (const float*)d_in[19]};

    // workspace layout (~122.7 MB)
    const size_t NBE = (size_t)NBK * BCAP;                          // 2,700,288
    uint2*    tmp      = (uint2*)d_ws;                              // 21.6 MB
    uint2*    cv       = tmp + NBE;                                 // 21.6 MB (+8 pad)
    uint16_t* side     = (uint16_t*)(cv + NBE + 8);                 // 38.4 MB
    uint16_t* ego      = side + (size_t)N_NODES * EMB;              // 38.4 MB
    unsigned long long* mask = (unsigned long long*)(ego + (size_t)N_NODES * EMB); // 250 KB
    uint32_t* rowstart = (uint32_t*)(mask + NNZ / 64);              // 1.2 MB
    uint32_t* rowend   = rowstart + N_NODES;                        // 1.2 MB
    uint32_t* bcnt     = rowend + N_NODES;                          // 9.4 KB
    float*    dotp     = (float*)(bcnt + NBK);                      // 16 KB
    float*    dotn     = dotp + BATCH;
    float*    sqs      = dotn + BATCH;
    size_t needed = (NBE * 2 + 8) * 8 + (size_t)N_NODES * EMB * 2 * 2
                  + (NNZ / 64) * 8 + ((size_t)2 * N_NODES + NBK + 3 * BATCH) * 4;
    if (ws_size < needed) return;

    // host-side JAX key derivation: key(42) = (0,42)
    uint32_t a0, b0, a1, b1;
    threefry2x32(0u, 42u, 0u, 2u, a0, b0);   // split block 0
    threefry2x32(0u, 42u, 1u, 3u, a1, b1);   // split block 1
    uint32_t knode0 = a0, knode1 = a1;       // k_node
    uint32_t kmsg0  = b0, kmsg1  = b1;       // k_msg
    uint32_t mk[6];
    for (uint32_t k = 0; k < 3; ++k)
        threefry2x32(kmsg0, kmsg1, 0u, k, mk[2 * k], mk[2 * k + 1]);

    hipMemsetAsync(bcnt, 0, (size_t)NBK * 4, stream);
    hipMemsetAsync(dotp, 0, 3 * BATCH * 4, stream);

    // ego (bf16) init + keep-mask + 2-level bucket CSR build
    k_conv<<<(N_NODES * EMB / 4 + 255) / 256, 256, 0, stream>>>(uemb, iemb, ego);
    k_mask<<<((int)R1M + 255) / 256, 256, 0, stream>>>(mask, knode0, knode1);
    k_bscatter<<<(NNZ + 255) / 256, 256, 0, stream>>>(erow, ecol, evals, mask, bcnt, tmp);
    k_bsort<<<NBK, 128, 0, stream>>>(tmp, bcnt, cv, rowstart, rowend);

    // segment 0: raw initial embeddings (fp32, exact)
    k_segacc<<<BATCH * 64 / 256, 256, 0, stream>>>(uemb, iemb, uid, iid, nid,
                                                   dotp, dotn, sqs, 0, 1);

    for (int k = 0; k < 3; ++k) {
        k_spmv<<<2048, 256, 0, stream>>>(ego, side, rowstart, rowend, cv);
        k_dense_mfma<<<768, 256, 0, stream>>>(ego, side, Wg[k], bg[k], Wb[k], bb[k],
                                              mk[2 * k], mk[2 * k + 1]);
        k_segacc<<<BATCH * 64 / 256, 256, 0, stream>>>(ego, ego + (size_t)USER_NUM * EMB,
                                                       uid, iid, nid, dotp, dotn, sqs, 1, 0);
    }
    k_finalize<<<1, 256, 0, stream>>>(dotp, dotn, sqs, (float*)d_out);
}

// Round 10
// 491.056 us; speedup vs baseline: 4.3623x; 1.3086x over previous
//
#include <hip/hip_runtime.h>
#include <stdint.h>

#define USER_NUM 100000
#define ITEM_NUM 200000
#define N_NODES  300000
#define EMB      64
#define NNZ      2000000
#define BATCH    4096
#define R1M      1000000u        // NNZ/2, threefry pair offset for edge dropout
#define HALF_MSG 9600000u        // N_NODES*EMB/2, pair offset for msg dropout
#define HALF_N   150000          // node pairing offset = HALF_MSG/64
#define INVK     1.1111111111111112f  // 1/0.9

#define NBK2     256             // coarse buckets (pass A)
#define BROWS    1172            // rows per bucket; 256*1172 = 300032
#define BCAP2    7680            // entries per bucket (mean 7032, +7.7 sigma)
#define ABLK     480             // pass-A blocks
#define ACH      4167            // edges per pass-A block
#define LDSCAP   3968            // LDS staging (kept mean 3750, +11 sigma)

typedef short short8 __attribute__((ext_vector_type(8)));
typedef float f32x4  __attribute__((ext_vector_type(4)));

// ---------------- threefry2x32 (exact JAX replica) ----------------
__host__ __device__ inline uint32_t rotl32(uint32_t v, int r) {
    return (v << r) | (v >> (32 - r));
}

__host__ __device__ inline void threefry2x32(uint32_t k0, uint32_t k1,
                                             uint32_t x0, uint32_t x1,
                                             uint32_t& o0, uint32_t& o1) {
    uint32_t k2 = k0 ^ k1 ^ 0x1BD11BDAu;
    x0 += k0; x1 += k1;
#define TF_R(r) { x0 += x1; x1 = rotl32(x1, r); x1 ^= x0; }
    TF_R(13) TF_R(15) TF_R(26) TF_R(6)
    x0 += k1; x1 += k2 + 1u;
    TF_R(17) TF_R(29) TF_R(16) TF_R(24)
    x0 += k2; x1 += k0 + 2u;
    TF_R(13) TF_R(15) TF_R(26) TF_R(6)
    x0 += k0; x1 += k1 + 3u;
    TF_R(17) TF_R(29) TF_R(16) TF_R(24)
    x0 += k1; x1 += k2 + 4u;
    TF_R(13) TF_R(15) TF_R(26) TF_R(6)
    x0 += k2; x1 += k0 + 5u;
#undef TF_R
    o0 = x0; o1 = x1;
}

__host__ __device__ inline float tf_uniform(uint32_t bits) {
    uint32_t fb = (bits >> 9) | 0x3f800000u;
    return __builtin_bit_cast(float, fb) - 1.0f;
}

// ---------------- bf16 helpers ----------------
__device__ inline float bf2f(uint16_t u) {
    uint32_t x = ((uint32_t)u) << 16;
    return __builtin_bit_cast(float, x);
}
__device__ inline uint16_t f2bf(float f) {   // round-to-nearest-even
    uint32_t x = __builtin_bit_cast(uint32_t, f);
    uint32_t r = (x + 0x7FFFu + ((x >> 16) & 1u)) >> 16;
    return (uint16_t)r;
}

// ---------------- ego init: concat(uemb,iemb) -> bf16 ----------------
__global__ __launch_bounds__(256) void k_conv(const float* __restrict__ u,
                                              const float* __restrict__ it,
                                              uint16_t* __restrict__ dst) {
    int i = blockIdx.x * 256 + threadIdx.x;     // quad index
    const int TOT = N_NODES * EMB / 4;          // 4.8M
    if (i >= TOT) return;
    const int UQ = USER_NUM * EMB / 4;
    float4 f = (i < UQ) ? ((const float4*)u)[i] : ((const float4*)it)[i - UQ];
    ushort4 o;
    o.x = f2bf(f.x); o.y = f2bf(f.y); o.z = f2bf(f.z); o.w = f2bf(f.w);
    ((ushort4*)dst)[i] = o;
}

// ---------------- sort pass A: LDS-binned coarse bucket sort ---------------
// Per block: keep-test + LDS histogram over 256 buckets -> scan -> one global
// reservation per (block,bucket) -> coalesced group writes.
__global__ __launch_bounds__(256) void k_sortA(const int* __restrict__ erow,
                                               const int* __restrict__ ecol,
                                               const float* __restrict__ evals,
                                               uint32_t* __restrict__ bcnt,
                                               uint2* __restrict__ tmp,
                                               uint32_t kn0, uint32_t kn1) {
    __shared__ uint32_t hist[NBK2];
    __shared__ uint32_t lstart[NBK2];
    __shared__ uint32_t gbase[NBK2];
    __shared__ uint32_t cur[NBK2];
    __shared__ uint32_t eidx[LDSCAP];
    __shared__ uint8_t  keepb[ACH];
    int tid = threadIdx.x;
    int base = blockIdx.x * ACH;
    int lim = min(ACH, NNZ - base);
    hist[tid] = 0u;
    __syncthreads();
    // phase 1: keep test + bucket histogram
    for (int j = tid; j < lim; j += 256) {
        uint32_t e = (uint32_t)(base + j);
        uint32_t x0 = (e < R1M) ? e : e - R1M;
        uint32_t o0, o1;
        threefry2x32(kn0, kn1, x0, x0 + R1M, o0, o1);
        uint32_t bits = (e < R1M) ? o0 : o1;
        bool kp = tf_uniform(bits) < 0.9f;
        keepb[j] = kp ? 1u : 0u;
        if (kp) atomicAdd(&hist[(uint32_t)erow[e] / BROWS], 1u);
    }
    __syncthreads();
    // 256-wide Hillis-Steele scan (in lstart)
    uint32_t x = hist[tid];
    lstart[tid] = x;
    __syncthreads();
    for (int off = 1; off < 256; off <<= 1) {
        uint32_t y = (tid >= off) ? lstart[tid - off] : 0u;
        __syncthreads();
        lstart[tid] += y;
        __syncthreads();
    }
    uint32_t exc = lstart[tid] - x;
    uint32_t gb = 0u;
    if (x) gb = atomicAdd(&bcnt[tid], x);   // one reservation per (block,bucket)
    lstart[tid] = exc;
    gbase[tid] = gb;
    cur[tid] = exc;
    __syncthreads();
    // phase 2: scatter kept edge ids into LDS, bucket-sorted
    for (int j = tid; j < lim; j += 256) {
        if (keepb[j]) {
            uint32_t e = (uint32_t)(base + j);
            uint32_t b = (uint32_t)erow[e] / BROWS;
            uint32_t p = atomicAdd(&cur[b], 1u);
            if (p < LDSCAP) eidx[p] = e;
        }
    }
    __syncthreads();
    uint32_t total = min(lstart[NBK2 - 1] + hist[NBK2 - 1], (uint32_t)LDSCAP);
    // phase 3: coalesced group write-out
    for (uint32_t p = tid; p < total; p += 256) {
        uint32_t e = eidx[p];
        uint32_t row = (uint32_t)erow[e];
        uint32_t b = row / BROWS;
        uint32_t off = gbase[b] + (p - lstart[b]);
        if (off < BCAP2) {
            uint2 q;
            q.x = (uint32_t)ecol[e] | ((row - b * BROWS) << 19);
            q.y = __builtin_bit_cast(uint32_t, evals[e] * INVK);
            tmp[(size_t)b * BCAP2 + off] = q;
        }
    }
}

// ---------------- sort pass B: within-bucket row sort ----------------------
// One block per 1172-row bucket; emits rowstart/rowend and row-sorted cv.
__global__ __launch_bounds__(256) void k_sortB(const uint2* __restrict__ tmp,
                                               const uint32_t* __restrict__ bcnt,
                                               uint2* __restrict__ cv,
                                               uint32_t* __restrict__ rowstart,
                                               uint32_t* __restrict__ rowend) {
    __shared__ uint32_t hist[1280];
    __shared__ uint32_t tsum[256];
    int b = blockIdx.x;
    int t = threadIdx.x;
    uint32_t cnt = min(bcnt[b], (uint32_t)BCAP2);
    for (int i = t; i < 1280; i += 256) hist[i] = 0u;
    __syncthreads();
    const uint2* src = tmp + (size_t)b * BCAP2;
    for (uint32_t i = t; i < cnt; i += 256)
        atomicAdd(&hist[src[i].x >> 19], 1u);
    __syncthreads();
    // two-level scan: thread t owns counters [5t, 5t+5)
    uint32_t l[5];
    uint32_t s = 0u;
#pragma unroll
    for (int i = 0; i < 5; ++i) { l[i] = hist[t * 5 + i]; s += l[i]; }
    tsum[t] = s;
    __syncthreads();
    for (int off = 1; off < 256; off <<= 1) {
        uint32_t y = (t >= off) ? tsum[t - off] : 0u;
        __syncthreads();
        tsum[t] += y;
        __syncthreads();
    }
    uint32_t run = tsum[t] - s;   // exclusive prefix at counter 5t
    uint32_t cvb = (uint32_t)b * BCAP2;
#pragma unroll
    for (int i = 0; i < 5; ++i) {
        uint32_t e0 = run;
        run += l[i];
        int idx = t * 5 + i;
        int row = b * BROWS + idx;
        if (idx < BROWS && row < N_NODES) {
            rowstart[row] = cvb + e0;
            rowend[row]   = cvb + run;
        }
        hist[idx] = e0;   // becomes cursor
    }
    __syncthreads();
    for (uint32_t i = t; i < cnt; i += 256) {
        uint2 p = src[i];
        uint32_t rl = p.x >> 19;
        uint32_t pos = atomicAdd(&hist[rl], 1u);
        uint2 q;
        q.x = p.x & 0x7FFFFu;
        q.y = p.y;
        cv[(size_t)cvb + pos] = q;
    }
}

// -------- SPMV: wave per row; scalar (SGPR) metadata, 8-deep gathers ------
__global__ __launch_bounds__(256) void k_spmv(const uint16_t* __restrict__ ego,
                                              uint16_t* __restrict__ side,
                                              const uint32_t* __restrict__ rowstart,
                                              const uint32_t* __restrict__ rowend,
                                              const uint2* __restrict__ cv) {
    int lane = threadIdx.x & 63;
    int wv = __builtin_amdgcn_readfirstlane((int)((blockIdx.x * 256 + threadIdx.x) >> 6));
    int nw = (gridDim.x * 256) >> 6;
    for (int n = wv; n < N_NODES; n += nw) {
        uint32_t st = __builtin_amdgcn_readfirstlane(rowstart[n]);
        uint32_t en = __builtin_amdgcn_readfirstlane(rowend[n]);
        float acc = 0.0f;
        for (uint32_t j0 = st; j0 < en; j0 += 8) {
            uint32_t cx[8];
            float vv[8];
#pragma unroll
            for (int u = 0; u < 8; ++u) {
                uint2 p = cv[j0 + u];            // uniform addr -> scalar load
                bool ok = (j0 + (uint32_t)u) < en;
                cx[u] = ok ? p.x : 0u;           // uniform selects (SALU)
                vv[u] = ok ? __builtin_bit_cast(float, p.y) : 0.0f;
            }
            float g[8];
#pragma unroll
            for (int u = 0; u < 8; ++u)
                g[u] = bf2f(ego[(size_t)cx[u] * 64 + lane]);
#pragma unroll
            for (int u = 0; u < 8; ++u)
                acc = fmaf(vv[u], g[u], acc);
        }
        side[(size_t)n * 64 + lane] = f2bf(acc);
    }
}

// -------- elementwise bf16 product frag: (side ∘ ego) --------
__device__ inline short8 mul_frag(short8 s, uint4 e) {
    uint32_t ew[4] = {e.x, e.y, e.z, e.w};
    short8 r;
#pragma unroll
    for (int i = 0; i < 4; ++i) {
        float a0 = bf2f((uint16_t)s[2 * i])     * bf2f((uint16_t)(ew[i] & 0xffffu));
        float a1 = bf2f((uint16_t)s[2 * i + 1]) * bf2f((uint16_t)(ew[i] >> 16));
        r[2 * i]     = (short)f2bf(a0);
        r[2 * i + 1] = (short)f2bf(a1);
    }
    return r;
}

// -------- dense via MFMA: [s | ego*s] (Nx128) @ [Wg;Wb] (128x64), in-place --
// Pair-tile (n0, n0+150000): one threefry per element pair serves both tiles.
__global__ __launch_bounds__(256) void k_dense_mfma(
        uint16_t* __restrict__ ego, const uint16_t* __restrict__ side,
        const float* __restrict__ Wg, const float* __restrict__ bg,
        const float* __restrict__ Wb, const float* __restrict__ bb,
        uint32_t km0, uint32_t km1) {
    int lane = threadIdx.x & 63;
    int wave = (blockIdx.x * 256 + threadIdx.x) >> 6;
    int nw = (gridDim.x * 256) >> 6;
    int m = lane & 15;     // A row within tile / C col within tile
    int g = lane >> 4;     // k-group (A) / row-group (C)

    short8 bfr[4][4];
#pragma unroll
    for (int kk = 0; kk < 4; ++kk) {
        const float* W = (kk < 2) ? Wg : Wb;
        int krow = (kk & 1) * 32 + 8 * g;
#pragma unroll
        for (int nt = 0; nt < 4; ++nt) {
#pragma unroll
            for (int i = 0; i < 8; ++i)
                bfr[kk][nt][i] = (short)f2bf(W[(krow + i) * 64 + 16 * nt + m]);
        }
    }
    float bias[4];
#pragma unroll
    for (int nt = 0; nt < 4; ++nt)
        bias[nt] = bg[16 * nt + m] + bb[16 * nt + m];

    for (int tile = wave; tile < HALF_N / 16; tile += nw) {
        int n0 = tile * 16;
        uint32_t keepB = 0;
        {
            const uint16_t* srow = side + (size_t)(n0 + m) * 64;
            const uint16_t* erw  = ego  + (size_t)(n0 + m) * 64;
            short8 a0 = *(const short8*)(srow + 8 * g);
            short8 a1 = *(const short8*)(srow + 32 + 8 * g);
            uint4  e0 = *(const uint4*)(erw + 8 * g);
            uint4  e1 = *(const uint4*)(erw + 32 + 8 * g);
            short8 a2 = mul_frag(a0, e0);
            short8 a3 = mul_frag(a1, e1);
            f32x4 acc[4];
#pragma unroll
            for (int nt = 0; nt < 4; ++nt) {
                acc[nt] = (f32x4)(0.0f);
                acc[nt] = __builtin_amdgcn_mfma_f32_16x16x32_bf16(a0, bfr[0][nt], acc[nt], 0, 0, 0);
                acc[nt] = __builtin_amdgcn_mfma_f32_16x16x32_bf16(a1, bfr[1][nt], acc[nt], 0, 0, 0);
                acc[nt] = __builtin_amdgcn_mfma_f32_16x16x32_bf16(a2, bfr[2][nt], acc[nt], 0, 0, 0);
                acc[nt] = __builtin_amdgcn_mfma_f32_16x16x32_bf16(a3, bfr[3][nt], acc[nt], 0, 0, 0);
            }
#pragma unroll
            for (int nt = 0; nt < 4; ++nt) {
#pragma unroll
                for (int i = 0; i < 4; ++i) {
                    int row = n0 + g * 4 + i;
                    int col = 16 * nt + m;
                    float h = acc[nt][i] + bias[nt];
                    h = (h >= 0.0f) ? h : 0.2f * h;
                    uint32_t j = (uint32_t)row * 64u + (uint32_t)col;
                    uint32_t o0, o1;
                    threefry2x32(km0, km1, j, j + HALF_MSG, o0, o1);
                    bool kA = tf_uniform(o0) < 0.9f;
                    keepB |= (uint32_t)(tf_uniform(o1) < 0.9f) << (nt * 4 + i);
                    ego[(size_t)row * 64 + col] = f2bf(kA ? h * INVK : 0.0f);
                }
            }
        }
        {
            int R = n0 + HALF_N;
            const uint16_t* srow = side + (size_t)(R + m) * 64;
            const uint16_t* erw  = ego  + (size_t)(R + m) * 64;
            short8 a0 = *(const short8*)(srow + 8 * g);
            short8 a1 = *(const short8*)(srow + 32 + 8 * g);
            uint4  e0 = *(const uint4*)(erw + 8 * g);
            uint4  e1 = *(const uint4*)(erw + 32 + 8 * g);
            short8 a2 = mul_frag(a0, e0);
            short8 a3 = mul_frag(a1, e1);
            f32x4 acc[4];
#pragma unroll
            for (int nt = 0; nt < 4; ++nt) {
                acc[nt] = (f32x4)(0.0f);
                acc[nt] = __builtin_amdgcn_mfma_f32_16x16x32_bf16(a0, bfr[0][nt], acc[nt], 0, 0, 0);
                acc[nt] = __builtin_amdgcn_mfma_f32_16x16x32_bf16(a1, bfr[1][nt], acc[nt], 0, 0, 0);
                acc[nt] = __builtin_amdgcn_mfma_f32_16x16x32_bf16(a2, bfr[2][nt], acc[nt], 0, 0, 0);
                acc[nt] = __builtin_amdgcn_mfma_f32_16x16x32_bf16(a3, bfr[3][nt], acc[nt], 0, 0, 0);
            }
#pragma unroll
            for (int nt = 0; nt < 4; ++nt) {
#pragma unroll
                for (int i = 0; i < 4; ++i) {
                    int row = R + g * 4 + i;
                    int col = 16 * nt + m;
                    float h = acc[nt][i] + bias[nt];
                    h = (h >= 0.0f) ? h : 0.2f * h;
                    bool kB = (keepB >> (nt * 4 + i)) & 1u;
                    ego[(size_t)row * 64 + col] = f2bf(kB ? h * INVK : 0.0f);
                }
            }
        }
    }
}

// ---------------- batch accumulation & finalize ----------------
__device__ inline float wred64(float v) {
#pragma unroll
    for (int m = 32; m >= 1; m >>= 1) v += __shfl_xor(v, m, 64);
    return v;
}

__global__ __launch_bounds__(256) void k_segacc(const void* __restrict__ ua_,
                                                const void* __restrict__ ia_,
                                                const int* __restrict__ uid,
                                                const int* __restrict__ iid,
                                                const int* __restrict__ nid,
                                                float* __restrict__ dotp,
                                                float* __restrict__ dotn,
                                                float* __restrict__ sqs,
                                                int normalize, int f32) {
    int gt = blockIdx.x * 256 + threadIdx.x;
    int w = gt >> 6, lane = gt & 63;
    if (w >= BATCH) return;
    int u = uid[w], p = iid[w], n = nid[w];
    float eu, ep, en;
    if (f32) {
        const float* ua = (const float*)ua_;
        const float* ia = (const float*)ia_;
        eu = ua[(size_t)u * EMB + lane];
        ep = ia[(size_t)p * EMB + lane];
        en = ia[(size_t)n * EMB + lane];
    } else {
        const uint16_t* ua = (const uint16_t*)ua_;
        const uint16_t* ia = (const uint16_t*)ia_;
        eu = bf2f(ua[(size_t)u * EMB + lane]);
        ep = bf2f(ia[(size_t)p * EMB + lane]);
        en = bf2f(ia[(size_t)n * EMB + lane]);
    }
    if (normalize) {
        float su = wred64(eu * eu);
        float sp = wred64(ep * ep);
        float sn = wred64(en * en);
        eu /= fmaxf(sqrtf(su), 1e-12f);
        ep /= fmaxf(sqrtf(sp), 1e-12f);
        en /= fmaxf(sqrtf(sn), 1e-12f);
    }
    float dp = wred64(eu * ep);
    float dn = wred64(eu * en);
    float s3 = wred64(eu * eu + ep * ep + en * en);
    if (lane == 0) {
        dotp[w] += dp;
        dotn[w] += dn;
        sqs[w]  += s3;
    }
}

__global__ __launch_bounds__(256) void k_finalize(const float* __restrict__ dotp,
                                                  const float* __restrict__ dotn,
                                                  const float* __restrict__ sqs,
                                                  float* __restrict__ out) {
    __shared__ float smf[256], ssq[256];
    int t = threadIdx.x;
    float mf = 0.0f, s = 0.0f;
    for (int b = t; b < BATCH; b += 256) {
        float x = dotp[b] - dotn[b];
        float ls = fminf(x, 0.0f) - log1pf(expf(-fabsf(x)));
        mf += ls;
        s += sqs[b];
    }
    smf[t] = mf; ssq[t] = s;
    __syncthreads();
    for (int off = 128; off > 0; off >>= 1) {
        if (t < off) { smf[t] += smf[t + off]; ssq[t] += ssq[t + off]; }
        __syncthreads();
    }
    if (t == 0) {
        float mf_loss = -smf[0] / (float)BATCH;
        float reg = 0.5f * ssq[0];
        float emb_loss = (float)1e-4 * reg / (float)BATCH;
        out[0] = mf_loss + emb_loss;
        out[1] = mf_loss;
        out[2] = emb_loss;
    }
}

// ---------------- launch ----------------
extern "C" void kernel_launch(void* const* d_in, const int* in_sizes, int n_in,
                              void* d_out, int out_size, void* d_ws, size_t ws_size,
                              hipStream_t stream) {
    const int*   erow  = (const int*)d_in[0];
    const int*   ecol  = (const int*)d_in[1];
    const float* evals = (const float*)d_in[2];
    const float* uemb  = (const float*)d_in[3];
    const float* iemb  = (const float*)d_in[4];
    const int*   uid   = (const int*)d_in[5];
    const int*   iid   = (const int*)d_in[6];
    const int*   nid   = (const int*)d_in[7];
    const float* Wg[3] = {(const float*)d_in[8],  (const float*)d_in[12], (const float*)d_in[16]};
    const float* bg[3] = {(const float*)d_in[9],  (const float*)d_in[13], (const float*)d_in[17]};
    const float* Wb[3] = {(const float*)d_in[10], (const float*)d_in[14], (const float*)d_in[18]};
    const float* bb[3] = {(const float*)d_in[11], (const float*)d_in[15], (const float*)d_in[19]};

    // workspace layout (~111 MB)
    const size_t NBE = (size_t)NBK2 * BCAP2;                        // 1,966,080
    uint2*    tmp      = (uint2*)d_ws;                              // 15.7 MB
    uint2*    cv       = tmp + NBE;                                 // 15.7 MB (+8 pad)
    uint16_t* side     = (uint16_t*)(cv + NBE + 8);                 // 38.4 MB
    uint16_t* ego      = side + (size_t)N_NODES * EMB;              // 38.4 MB
    uint32_t* rowstart = (uint32_t*)(ego + (size_t)N_NODES * EMB);  // 1.2 MB
    uint32_t* rowend   = rowstart + N_NODES;                        // 1.2 MB
    uint32_t* bcnt     = rowend + N_NODES;                          // 1 KB
    float*    dotp     = (float*)(bcnt + NBK2);                     // 16 KB
    float*    dotn     = dotp + BATCH;
    float*    sqs      = dotn + BATCH;
    size_t needed = (NBE * 2 + 8) * 8 + (size_t)N_NODES * EMB * 2 * 2
                  + ((size_t)2 * N_NODES + NBK2 + 3 * BATCH) * 4;
    if (ws_size < needed) return;

    // host-side JAX key derivation: key(42) = (0,42)
    uint32_t a0, b0, a1, b1;
    threefry2x32(0u, 42u, 0u, 2u, a0, b0);   // split block 0
    threefry2x32(0u, 42u, 1u, 3u, a1, b1);   // split block 1
    uint32_t knode0 = a0, knode1 = a1;       // k_node
    uint32_t kmsg0  = b0, kmsg1  = b1;       // k_msg
    uint32_t mk[6];
    for (uint32_t k = 0; k < 3; ++k)
        threefry2x32(kmsg0, kmsg1, 0u, k, mk[2 * k], mk[2 * k + 1]);

    hipMemsetAsync(bcnt, 0, (size_t)NBK2 * 4, stream);
    hipMemsetAsync(dotp, 0, 3 * BATCH * 4, stream);

    // ego (bf16) init + two-pass LDS-binned CSR build
    k_conv<<<(N_NODES * EMB / 4 + 255) / 256, 256, 0, stream>>>(uemb, iemb, ego);
    k_sortA<<<ABLK, 256, 0, stream>>>(erow, ecol, evals, bcnt, tmp, knode0, knode1);
    k_sortB<<<NBK2, 256, 0, stream>>>(tmp, bcnt, cv, rowstart, rowend);

    // segment 0: raw initial embeddings (fp32, exact)
    k_segacc<<<BATCH * 64 / 256, 256, 0, stream>>>(uemb, iemb, uid, iid, nid,
                                                   dotp, dotn, sqs, 0, 1);

    for (int k = 0; k < 3; ++k) {
        k_spmv<<<2048, 256, 0, stream>>>(ego, side, rowstart, rowend, cv);
        k_dense_mfma<<<768, 256, 0, stream>>>(ego, side, Wg[k], bg[k], Wb[k], bb[k],
                                              mk[2 * k], mk[2 * k + 1]);
        k_segacc<<<BATCH * 64 / 256, 256, 0, stream>>>(ego, ego + (size_t)USER_NUM * EMB,
                                                       uid, iid, nid, dotp, dotn, sqs, 1, 0);
    }
    k_finalize<<<1, 256, 0, stream>>>(dotp, dotn, sqs, (float*)d_out);
}

// Round 11
// 470.635 us; speedup vs baseline: 4.5515x; 1.0434x over previous
//
#include <hip/hip_runtime.h>
#include <stdint.h>

#define USER_NUM 100000
#define ITEM_NUM 200000
#define N_NODES  300000
#define EMB      64
#define NNZ      2000000
#define BATCH    4096
#define R1M      1000000u        // NNZ/2, threefry pair offset for edge dropout
#define HALF_MSG 9600000u        // N_NODES*EMB/2, pair offset for msg dropout
#define HALF_N   150000          // node pairing offset = HALF_MSG/64
#define INVK     1.1111111111111112f  // 1/0.9

#define NBK2     256             // coarse buckets (pass A)
#define BROWS    1172            // rows per bucket (even!); 256*1172 = 300032
#define BCAP2    7680            // entries per bucket (mean 7032, +7.7 sigma)
#define ABLK     480             // pass-A blocks
#define ACH      4167            // edges per pass-A block
#define LDSCAP   3968            // LDS staging (kept mean 3750, +11 sigma)

typedef short short8 __attribute__((ext_vector_type(8)));
typedef float f32x4  __attribute__((ext_vector_type(4)));

// ---------------- threefry2x32 (exact JAX replica) ----------------
__host__ __device__ inline uint32_t rotl32(uint32_t v, int r) {
    return (v << r) | (v >> (32 - r));
}

__host__ __device__ inline void threefry2x32(uint32_t k0, uint32_t k1,
                                             uint32_t x0, uint32_t x1,
                                             uint32_t& o0, uint32_t& o1) {
    uint32_t k2 = k0 ^ k1 ^ 0x1BD11BDAu;
    x0 += k0; x1 += k1;
#define TF_R(r) { x0 += x1; x1 = rotl32(x1, r); x1 ^= x0; }
    TF_R(13) TF_R(15) TF_R(26) TF_R(6)
    x0 += k1; x1 += k2 + 1u;
    TF_R(17) TF_R(29) TF_R(16) TF_R(24)
    x0 += k2; x1 += k0 + 2u;
    TF_R(13) TF_R(15) TF_R(26) TF_R(6)
    x0 += k0; x1 += k1 + 3u;
    TF_R(17) TF_R(29) TF_R(16) TF_R(24)
    x0 += k1; x1 += k2 + 4u;
    TF_R(13) TF_R(15) TF_R(26) TF_R(6)
    x0 += k2; x1 += k0 + 5u;
#undef TF_R
    o0 = x0; o1 = x1;
}

__host__ __device__ inline float tf_uniform(uint32_t bits) {
    uint32_t fb = (bits >> 9) | 0x3f800000u;
    return __builtin_bit_cast(float, fb) - 1.0f;
}

// ---------------- bf16 helpers ----------------
__device__ inline float bf2f(uint16_t u) {
    uint32_t x = ((uint32_t)u) << 16;
    return __builtin_bit_cast(float, x);
}
__device__ inline uint16_t f2bf(float f) {   // round-to-nearest-even
    uint32_t x = __builtin_bit_cast(uint32_t, f);
    uint32_t r = (x + 0x7FFFu + ((x >> 16) & 1u)) >> 16;
    return (uint16_t)r;
}

// ---------------- ego init: concat(uemb,iemb) -> bf16 ----------------
__global__ __launch_bounds__(256) void k_conv(const float* __restrict__ u,
                                              const float* __restrict__ it,
                                              uint16_t* __restrict__ dst) {
    int i = blockIdx.x * 256 + threadIdx.x;     // quad index
    const int TOT = N_NODES * EMB / 4;          // 4.8M
    if (i >= TOT) return;
    const int UQ = USER_NUM * EMB / 4;
    float4 f = (i < UQ) ? ((const float4*)u)[i] : ((const float4*)it)[i - UQ];
    ushort4 o;
    o.x = f2bf(f.x); o.y = f2bf(f.y); o.z = f2bf(f.z); o.w = f2bf(f.w);
    ((ushort4*)dst)[i] = o;
}

// ---------------- sort pass A: LDS-binned coarse bucket sort ---------------
__global__ __launch_bounds__(256) void k_sortA(const int* __restrict__ erow,
                                               const int* __restrict__ ecol,
                                               const float* __restrict__ evals,
                                               uint32_t* __restrict__ bcnt,
                                               uint2* __restrict__ tmp,
                                               uint32_t kn0, uint32_t kn1) {
    __shared__ uint32_t hist[NBK2];
    __shared__ uint32_t lstart[NBK2];
    __shared__ uint32_t gbase[NBK2];
    __shared__ uint32_t cur[NBK2];
    __shared__ uint32_t eidx[LDSCAP];
    __shared__ uint8_t  keepb[ACH];
    int tid = threadIdx.x;
    int base = blockIdx.x * ACH;
    int lim = min(ACH, NNZ - base);
    hist[tid] = 0u;
    __syncthreads();
    for (int j = tid; j < lim; j += 256) {
        uint32_t e = (uint32_t)(base + j);
        uint32_t x0 = (e < R1M) ? e : e - R1M;
        uint32_t o0, o1;
        threefry2x32(kn0, kn1, x0, x0 + R1M, o0, o1);
        uint32_t bits = (e < R1M) ? o0 : o1;
        bool kp = tf_uniform(bits) < 0.9f;
        keepb[j] = kp ? 1u : 0u;
        if (kp) atomicAdd(&hist[(uint32_t)erow[e] / BROWS], 1u);
    }
    __syncthreads();
    uint32_t x = hist[tid];
    lstart[tid] = x;
    __syncthreads();
    for (int off = 1; off < 256; off <<= 1) {
        uint32_t y = (tid >= off) ? lstart[tid - off] : 0u;
        __syncthreads();
        lstart[tid] += y;
        __syncthreads();
    }
    uint32_t exc = lstart[tid] - x;
    uint32_t gb = 0u;
    if (x) gb = atomicAdd(&bcnt[tid], x);
    lstart[tid] = exc;
    gbase[tid] = gb;
    cur[tid] = exc;
    __syncthreads();
    for (int j = tid; j < lim; j += 256) {
        if (keepb[j]) {
            uint32_t e = (uint32_t)(base + j);
            uint32_t b = (uint32_t)erow[e] / BROWS;
            uint32_t p = atomicAdd(&cur[b], 1u);
            if (p < LDSCAP) eidx[p] = e;
        }
    }
    __syncthreads();
    uint32_t total = min(lstart[NBK2 - 1] + hist[NBK2 - 1], (uint32_t)LDSCAP);
    for (uint32_t p = tid; p < total; p += 256) {
        uint32_t e = eidx[p];
        uint32_t row = (uint32_t)erow[e];
        uint32_t b = row / BROWS;
        uint32_t off = gbase[b] + (p - lstart[b]);
        if (off < BCAP2) {
            uint2 q;
            q.x = (uint32_t)ecol[e] | ((row - b * BROWS) << 19);
            q.y = __builtin_bit_cast(uint32_t, evals[e] * INVK);
            tmp[(size_t)b * BCAP2 + off] = q;
        }
    }
}

// ---------------- sort pass B: within-bucket row sort ----------------------
__global__ __launch_bounds__(256) void k_sortB(const uint2* __restrict__ tmp,
                                               const uint32_t* __restrict__ bcnt,
                                               uint2* __restrict__ cv,
                                               uint32_t* __restrict__ rowstart,
                                               uint32_t* __restrict__ rowend) {
    __shared__ uint32_t hist[1280];
    __shared__ uint32_t tsum[256];
    int b = blockIdx.x;
    int t = threadIdx.x;
    uint32_t cnt = min(bcnt[b], (uint32_t)BCAP2);
    for (int i = t; i < 1280; i += 256) hist[i] = 0u;
    __syncthreads();
    const uint2* src = tmp + (size_t)b * BCAP2;
    for (uint32_t i = t; i < cnt; i += 256)
        atomicAdd(&hist[src[i].x >> 19], 1u);
    __syncthreads();
    uint32_t l[5];
    uint32_t s = 0u;
#pragma unroll
    for (int i = 0; i < 5; ++i) { l[i] = hist[t * 5 + i]; s += l[i]; }
    tsum[t] = s;
    __syncthreads();
    for (int off = 1; off < 256; off <<= 1) {
        uint32_t y = (t >= off) ? tsum[t - off] : 0u;
        __syncthreads();
        tsum[t] += y;
        __syncthreads();
    }
    uint32_t run = tsum[t] - s;
    uint32_t cvb = (uint32_t)b * BCAP2;
#pragma unroll
    for (int i = 0; i < 5; ++i) {
        uint32_t e0 = run;
        run += l[i];
        int idx = t * 5 + i;
        int row = b * BROWS + idx;
        if (idx < BROWS && row < N_NODES) {
            rowstart[row] = cvb + e0;
            rowend[row]   = cvb + run;
        }
        hist[idx] = e0;
    }
    __syncthreads();
    for (uint32_t i = t; i < cnt; i += 256) {
        uint2 p = src[i];
        uint32_t rl = p.x >> 19;
        uint32_t pos = atomicAdd(&hist[rl], 1u);
        uint2 q;
        q.x = p.x & 0x7FFFFu;
        q.y = p.y;
        cv[(size_t)cvb + pos] = q;
    }
}

// -------- SPMV: 2 adjacent rows per wave as ONE contiguous segment --------
// rowend[n] == rowstart[n+1] within a bucket (BROWS even => even-n pairs
// never straddle). One scalar metadata fetch per pair, 8-deep gathers over
// the merged segment, dual-FMA routing with SALU-selected weights.
__global__ __launch_bounds__(256) void k_spmv(const uint16_t* __restrict__ ego,
                                              uint16_t* __restrict__ side,
                                              const uint32_t* __restrict__ rowstart,
                                              const uint32_t* __restrict__ rowend,
                                              const uint2* __restrict__ cv) {
    int lane = threadIdx.x & 63;
    int wv = __builtin_amdgcn_readfirstlane((int)((blockIdx.x * 256 + threadIdx.x) >> 6));
    int nw = (gridDim.x * 256) >> 6;
    for (int n0 = wv * 2; n0 < N_NODES; n0 += nw * 2) {
        uint32_t st  = __builtin_amdgcn_readfirstlane(rowstart[n0]);
        uint32_t mid = __builtin_amdgcn_readfirstlane(rowend[n0]);
        uint32_t en  = __builtin_amdgcn_readfirstlane(rowend[n0 + 1]);
        float acc0 = 0.0f, acc1 = 0.0f;
        for (uint32_t j0 = st; j0 < en; j0 += 8) {
            uint32_t cx[8];
            float v0[8], v1[8];
#pragma unroll
            for (int u = 0; u < 8; ++u) {
                uint2 p = cv[j0 + u];            // uniform addr -> scalar load
                uint32_t idx = j0 + (uint32_t)u;
                bool ok = idx < en;
                bool r1 = idx >= mid;
                cx[u] = ok ? p.x : 0u;
                float v = ok ? __builtin_bit_cast(float, p.y) : 0.0f;
                v0[u] = r1 ? 0.0f : v;           // uniform selects (SALU)
                v1[u] = r1 ? v : 0.0f;
            }
            float g[8];
#pragma unroll
            for (int u = 0; u < 8; ++u)
                g[u] = bf2f(ego[(size_t)cx[u] * 64 + lane]);
#pragma unroll
            for (int u = 0; u < 8; ++u) {
                acc0 = fmaf(v0[u], g[u], acc0);
                acc1 = fmaf(v1[u], g[u], acc1);
            }
        }
        side[(size_t)n0 * 64 + lane] = f2bf(acc0);
        side[(size_t)(n0 + 1) * 64 + lane] = f2bf(acc1);
    }
}

// -------- elementwise bf16 product frag: (side ∘ ego) --------
__device__ inline short8 mul_frag(short8 s, uint4 e) {
    uint32_t ew[4] = {e.x, e.y, e.z, e.w};
    short8 r;
#pragma unroll
    for (int i = 0; i < 4; ++i) {
        float a0 = bf2f((uint16_t)s[2 * i])     * bf2f((uint16_t)(ew[i] & 0xffffu));
        float a1 = bf2f((uint16_t)s[2 * i + 1]) * bf2f((uint16_t)(ew[i] >> 16));
        r[2 * i]     = (short)f2bf(a0);
        r[2 * i + 1] = (short)f2bf(a1);
    }
    return r;
}

// -------- dense via MFMA: [s | ego*s] (Nx128) @ [Wg;Wb] (128x64), in-place --
__global__ __launch_bounds__(256) void k_dense_mfma(
        uint16_t* __restrict__ ego, const uint16_t* __restrict__ side,
        const float* __restrict__ Wg, const float* __restrict__ bg,
        const float* __restrict__ Wb, const float* __restrict__ bb,
        uint32_t km0, uint32_t km1) {
    int lane = threadIdx.x & 63;
    int wave = (blockIdx.x * 256 + threadIdx.x) >> 6;
    int nw = (gridDim.x * 256) >> 6;
    int m = lane & 15;     // A row within tile / C col within tile
    int g = lane >> 4;     // k-group (A) / row-group (C)

    short8 bfr[4][4];
#pragma unroll
    for (int kk = 0; kk < 4; ++kk) {
        const float* W = (kk < 2) ? Wg : Wb;
        int krow = (kk & 1) * 32 + 8 * g;
#pragma unroll
        for (int nt = 0; nt < 4; ++nt) {
#pragma unroll
            for (int i = 0; i < 8; ++i)
                bfr[kk][nt][i] = (short)f2bf(W[(krow + i) * 64 + 16 * nt + m]);
        }
    }
    float bias[4];
#pragma unroll
    for (int nt = 0; nt < 4; ++nt)
        bias[nt] = bg[16 * nt + m] + bb[16 * nt + m];

    for (int tile = wave; tile < HALF_N / 16; tile += nw) {
        int n0 = tile * 16;
        uint32_t keepB = 0;
        {
            const uint16_t* srow = side + (size_t)(n0 + m) * 64;
            const uint16_t* erw  = ego  + (size_t)(n0 + m) * 64;
            short8 a0 = *(const short8*)(srow + 8 * g);
            short8 a1 = *(const short8*)(srow + 32 + 8 * g);
            uint4  e0 = *(const uint4*)(erw + 8 * g);
            uint4  e1 = *(const uint4*)(erw + 32 + 8 * g);
            short8 a2 = mul_frag(a0, e0);
            short8 a3 = mul_frag(a1, e1);
            f32x4 acc[4];
#pragma unroll
            for (int nt = 0; nt < 4; ++nt) {
                acc[nt] = (f32x4)(0.0f);
                acc[nt] = __builtin_amdgcn_mfma_f32_16x16x32_bf16(a0, bfr[0][nt], acc[nt], 0, 0, 0);
                acc[nt] = __builtin_amdgcn_mfma_f32_16x16x32_bf16(a1, bfr[1][nt], acc[nt], 0, 0, 0);
                acc[nt] = __builtin_amdgcn_mfma_f32_16x16x32_bf16(a2, bfr[2][nt], acc[nt], 0, 0, 0);
                acc[nt] = __builtin_amdgcn_mfma_f32_16x16x32_bf16(a3, bfr[3][nt], acc[nt], 0, 0, 0);
            }
#pragma unroll
            for (int nt = 0; nt < 4; ++nt) {
#pragma unroll
                for (int i = 0; i < 4; ++i) {
                    int row = n0 + g * 4 + i;
                    int col = 16 * nt + m;
                    float h = acc[nt][i] + bias[nt];
                    h = (h >= 0.0f) ? h : 0.2f * h;
                    uint32_t j = (uint32_t)row * 64u + (uint32_t)col;
                    uint32_t o0, o1;
                    threefry2x32(km0, km1, j, j + HALF_MSG, o0, o1);
                    bool kA = tf_uniform(o0) < 0.9f;
                    keepB |= (uint32_t)(tf_uniform(o1) < 0.9f) << (nt * 4 + i);
                    ego[(size_t)row * 64 + col] = f2bf(kA ? h * INVK : 0.0f);
                }
            }
        }
        {
            int R = n0 + HALF_N;
            const uint16_t* srow = side + (size_t)(R + m) * 64;
            const uint16_t* erw  = ego  + (size_t)(R + m) * 64;
            short8 a0 = *(const short8*)(srow + 8 * g);
            short8 a1 = *(const short8*)(srow + 32 + 8 * g);
            uint4  e0 = *(const uint4*)(erw + 8 * g);
            uint4  e1 = *(const uint4*)(erw + 32 + 8 * g);
            short8 a2 = mul_frag(a0, e0);
            short8 a3 = mul_frag(a1, e1);
            f32x4 acc[4];
#pragma unroll
            for (int nt = 0; nt < 4; ++nt) {
                acc[nt] = (f32x4)(0.0f);
                acc[nt] = __builtin_amdgcn_mfma_f32_16x16x32_bf16(a0, bfr[0][nt], acc[nt], 0, 0, 0);
                acc[nt] = __builtin_amdgcn_mfma_f32_16x16x32_bf16(a1, bfr[1][nt], acc[nt], 0, 0, 0);
                acc[nt] = __builtin_amdgcn_mfma_f32_16x16x32_bf16(a2, bfr[2][nt], acc[nt], 0, 0, 0);
                acc[nt] = __builtin_amdgcn_mfma_f32_16x16x32_bf16(a3, bfr[3][nt], acc[nt], 0, 0, 0);
            }
#pragma unroll
            for (int nt = 0; nt < 4; ++nt) {
#pragma unroll
                for (int i = 0; i < 4; ++i) {
                    int row = R + g * 4 + i;
                    int col = 16 * nt + m;
                    float h = acc[nt][i] + bias[nt];
                    h = (h >= 0.0f) ? h : 0.2f * h;
                    bool kB = (keepB >> (nt * 4 + i)) & 1u;
                    ego[(size_t)row * 64 + col] = f2bf(kB ? h * INVK : 0.0f);
                }
            }
        }
    }
}

// ---------------- batch accumulation & finalize ----------------
__device__ inline float wred64(float v) {
#pragma unroll
    for (int m = 32; m >= 1; m >>= 1) v += __shfl_xor(v, m, 64);
    return v;
}

__global__ __launch_bounds__(256) void k_segacc(const void* __restrict__ ua_,
                                                const void* __restrict__ ia_,
                                                const int* __restrict__ uid,
                                                const int* __restrict__ iid,
                                                const int* __restrict__ nid,
                                                float* __restrict__ dotp,
                                                float* __restrict__ dotn,
                                                float* __restrict__ sqs,
                                                int normalize, int f32) {
    int gt = blockIdx.x * 256 + threadIdx.x;
    int w = gt >> 6, lane = gt & 63;
    if (w >= BATCH) return;
    int u = uid[w], p = iid[w], n = nid[w];
    float eu, ep, en;
    if (f32) {
        const float* ua = (const float*)ua_;
        const float* ia = (const float*)ia_;
        eu = ua[(size_t)u * EMB + lane];
        ep = ia[(size_t)p * EMB + lane];
        en = ia[(size_t)n * EMB + lane];
    } else {
        const uint16_t* ua = (const uint16_t*)ua_;
        const uint16_t* ia = (const uint16_t*)ia_;
        eu = bf2f(ua[(size_t)u * EMB + lane]);
        ep = bf2f(ia[(size_t)p * EMB + lane]);
        en = bf2f(ia[(size_t)n * EMB + lane]);
    }
    if (normalize) {
        float su = wred64(eu * eu);
        float sp = wred64(ep * ep);
        float sn = wred64(en * en);
        eu /= fmaxf(sqrtf(su), 1e-12f);
        ep /= fmaxf(sqrtf(sp), 1e-12f);
        en /= fmaxf(sqrtf(sn), 1e-12f);
    }
    float dp = wred64(eu * ep);
    float dn = wred64(eu * en);
    float s3 = wred64(eu * eu + ep * ep + en * en);
    if (lane == 0) {
        dotp[w] += dp;
        dotn[w] += dn;
        sqs[w]  += s3;
    }
}

__global__ __launch_bounds__(256) void k_finalize(const float* __restrict__ dotp,
                                                  const float* __restrict__ dotn,
                                                  const float* __restrict__ sqs,
                                                  float* __restrict__ out) {
    __shared__ float smf[256], ssq[256];
    int t = threadIdx.x;
    float mf = 0.0f, s = 0.0f;
    for (int b = t; b < BATCH; b += 256) {
        float x = dotp[b] - dotn[b];
        float ls = fminf(x, 0.0f) - log1pf(expf(-fabsf(x)));
        mf += ls;
        s += sqs[b];
    }
    smf[t] = mf; ssq[t] = s;
    __syncthreads();
    for (int off = 128; off > 0; off >>= 1) {
        if (t < off) { smf[t] += smf[t + off]; ssq[t] += ssq[t + off]; }
        __syncthreads();
    }
    if (t == 0) {
        float mf_loss = -smf[0] / (float)BATCH;
        float reg = 0.5f * ssq[0];
        float emb_loss = (float)1e-4 * reg / (float)BATCH;
        out[0] = mf_loss + emb_loss;
        out[1] = mf_loss;
        out[2] = emb_loss;
    }
}

// ---------------- launch ----------------
extern "C" void kernel_launch(void* const* d_in, const int* in_sizes, int n_in,
                              void* d_out, int out_size, void* d_ws, size_t ws_size,
                              hipStream_t stream) {
    const int*   erow  = (const int*)d_in[0];
    const int*   ecol  = (const int*)d_in[1];
    const float* evals = (const float*)d_in[2];
    const float* uemb  = (const float*)d_in[3];
    const float* iemb  = (const float*)d_in[4];
    const int*   uid   = (const int*)d_in[5];
    const int*   iid   = (const int*)d_in[6];
    const int*   nid   = (const int*)d_in[7];
    const float* Wg[3] = {(const float*)d_in[8],  (const float*)d_in[12], (const float*)d_in[16]};
    const float* bg[3] = {(const float*)d_in[9],  (const float*)d_in[13], (const float*)d_in[17]};
    const float* Wb[3] = {(const float*)d_in[10], (const float*)d_in[14], (const float*)d_in[18]};
    const float* bb[3] = {(const float*)d_in[11], (const float*)d_in[15], (const float*)d_in[19]};

    // workspace layout (~111 MB)
    const size_t NBE = (size_t)NBK2 * BCAP2;                        // 1,966,080
    uint2*    tmp      = (uint2*)d_ws;                              // 15.7 MB
    uint2*    cv       = tmp + NBE;                                 // 15.7 MB (+8 pad)
    uint16_t* side     = (uint16_t*)(cv + NBE + 8);                 // 38.4 MB
    uint16_t* ego      = side + (size_t)N_NODES * EMB;              // 38.4 MB
    uint32_t* rowstart = (uint32_t*)(ego + (size_t)N_NODES * EMB);  // 1.2 MB
    uint32_t* rowend   = rowstart + N_NODES;                        // 1.2 MB
    uint32_t* bcnt     = rowend + N_NODES;                          // 1 KB
    float*    dotp     = (float*)(bcnt + NBK2);                     // 16 KB
    float*    dotn     = dotp + BATCH;
    float*    sqs      = dotn + BATCH;
    size_t needed = (NBE * 2 + 8) * 8 + (size_t)N_NODES * EMB * 2 * 2
                  + ((size_t)2 * N_NODES + NBK2 + 3 * BATCH) * 4;
    if (ws_size < needed) return;

    // host-side JAX key derivation: key(42) = (0,42)
    uint32_t a0, b0, a1, b1;
    threefry2x32(0u, 42u, 0u, 2u, a0, b0);   // split block 0
    threefry2x32(0u, 42u, 1u, 3u, a1, b1);   // split block 1
    uint32_t knode0 = a0, knode1 = a1;       // k_node
    uint32_t kmsg0  = b0, kmsg1  = b1;       // k_msg
    uint32_t mk[6];
    for (uint32_t k = 0; k < 3; ++k)
        threefry2x32(kmsg0, kmsg1, 0u, k, mk[2 * k], mk[2 * k + 1]);

    hipMemsetAsync(bcnt, 0, (size_t)NBK2 * 4, stream);
    hipMemsetAsync(dotp, 0, 3 * BATCH * 4, stream);

    // ego (bf16) init + two-pass LDS-binned CSR build
    k_conv<<<(N_NODES * EMB / 4 + 255) / 256, 256, 0, stream>>>(uemb, iemb, ego);
    k_sortA<<<ABLK, 256, 0, stream>>>(erow, ecol, evals, bcnt, tmp, knode0, knode1);
    k_sortB<<<NBK2, 256, 0, stream>>>(tmp, bcnt, cv, rowstart, rowend);

    // segment 0: raw initial embeddings (fp32, exact)
    k_segacc<<<BATCH * 64 / 256, 256, 0, stream>>>(uemb, iemb, uid, iid, nid,
                                                   dotp, dotn, sqs, 0, 1);

    for (int k = 0; k < 3; ++k) {
        k_spmv<<<2048, 256, 0, stream>>>(ego, side, rowstart, rowend, cv);
        k_dense_mfma<<<768, 256, 0, stream>>>(ego, side, Wg[k], bg[k], Wb[k], bb[k],
                                              mk[2 * k], mk[2 * k + 1]);
        k_segacc<<<BATCH * 64 / 256, 256, 0, stream>>>(ego, ego + (size_t)USER_NUM * EMB,
                                                       uid, iid, nid, dotp, dotn, sqs, 1, 0);
    }
    k_finalize<<<1, 256, 0, stream>>>(dotp, dotn, sqs, (float*)d_out);
}